// Round 1
// baseline (1051.900 us; speedup 1.0000x reference)
//
#include <hip/hip_runtime.h>

#define N_NODES 50000
#define IN_DIM  512
#define OUT_DIM 128
#define BN_EPS  1e-5f

// ---------------- CSR build ----------------

__global__ void init_kernel(int* __restrict__ cnt, float* __restrict__ stats, int n) {
    int i = blockIdx.x * blockDim.x + threadIdx.x;
    if (i < n) cnt[i] = 1;            // self-loop contributes 1 to every in-degree
    if (i < 512) stats[i] = 0.f;      // zero BN stat accumulators (both layers)
}

// Detect whether edge_index arrived as int64 (viewed as int32 pairs) or int32.
// Values are < 50000, so in int64 mode the odd int32 slots are all zero.
__device__ __forceinline__ int edge_is64(const int* ei) {
    return (ei[1] | ei[3] | ei[5] | ei[7]) == 0;
}

__global__ void deg_kernel(const int* __restrict__ ei, int* __restrict__ cnt, int E) {
    int e = blockIdx.x * blockDim.x + threadIdx.x;
    if (e >= E) return;
    int is64 = edge_is64(ei);
    int dst = is64 ? ei[2 * E + 2 * e] : ei[E + e];
    atomicAdd(&cnt[dst], 1);
}

// Single-block exclusive scan of cnt[0..n) -> rowp[0..n]
__global__ void scan_kernel(const int* __restrict__ cnt, int* __restrict__ rowp, int n) {
    __shared__ int sd[1024];
    __shared__ int soff;
    const int tid = threadIdx.x;
    if (tid == 0) soff = 0;
    __syncthreads();
    for (int base = 0; base < n; base += 1024) {
        int i = base + tid;
        int v = (i < n) ? cnt[i] : 0;
        sd[tid] = v;
        __syncthreads();
        for (int s = 1; s < 1024; s <<= 1) {
            int t = (tid >= s) ? sd[tid - s] : 0;
            __syncthreads();
            sd[tid] += t;
            __syncthreads();
        }
        int off = soff;
        if (i < n) rowp[i] = off + sd[tid] - v;   // exclusive
        __syncthreads();
        if (tid == 1023) soff += sd[1023];
        __syncthreads();
    }
    if (tid == 0) rowp[n] = soff;
}

// dinv, write self-loop entry, init fill cursor (reuses cnt)
__global__ void selfloop_kernel(int* __restrict__ cnt, const int* __restrict__ rowp,
                                float* __restrict__ dinv, int* __restrict__ col, int n) {
    int i = blockIdx.x * blockDim.x + threadIdx.x;
    if (i >= n) return;
    int deg = cnt[i];
    dinv[i] = rsqrtf(fmaxf((float)deg, 1.f));
    int rp = rowp[i];
    col[rp] = i;          // self loop first
    cnt[i] = rp + 1;      // cursor for edge fill
}

__global__ void fill_kernel(const int* __restrict__ ei, int* __restrict__ cnt,
                            int* __restrict__ col, int E) {
    int e = blockIdx.x * blockDim.x + threadIdx.x;
    if (e >= E) return;
    int is64 = edge_is64(ei);
    int src, dst;
    if (is64) { src = ei[2 * e];     dst = ei[2 * E + 2 * e]; }
    else      { src = ei[e];         dst = ei[E + e]; }
    int pos = atomicAdd(&cnt[dst], 1);
    col[pos] = src;
}

// ---------------- GEMM (fp32, 128x128 tile, 8x8 per thread) ----------------
// XFORM: apply per-column BN scale/shift + PReLU to A elements on load.

template <int K, bool XFORM>
__global__ __launch_bounds__(256) void gemm_kernel(
        const float* __restrict__ A, const float* __restrict__ W,
        float* __restrict__ out, int M,
        const float* __restrict__ bnp, const float* __restrict__ alpha_p) {
    __shared__ float As[16][132];   // A^T tile: [k][m], row stride 132 floats (528B, 16B-aligned)
    __shared__ float Bs[16][132];   // B tile:   [k][nout]
    const int tid = threadIdx.x;
    const int tx = tid & 15;
    const int ty = tid >> 4;
    const int row0 = blockIdx.x * 128;
    float alpha = 0.f;
    if (XFORM) alpha = alpha_p[0];

    float acc[8][8];
#pragma unroll
    for (int i = 0; i < 8; i++)
#pragma unroll
        for (int j = 0; j < 8; j++) acc[i][j] = 0.f;

    for (int k0 = 0; k0 < K; k0 += 16) {
        // A tile: 128 rows x 16 cols = 512 float4 loads
#pragma unroll
        for (int l = 0; l < 2; l++) {
            int idx = tid + l * 256;
            int r = idx >> 2;
            int c4 = (idx & 3) << 2;
            int gr = row0 + r;
            float4 v = make_float4(0.f, 0.f, 0.f, 0.f);
            if (gr < M) v = *(const float4*)(A + (size_t)gr * K + (k0 + c4));
            if (XFORM) {
                int c = k0 + c4;
                float s0 = bnp[c], s1 = bnp[c + 1], s2 = bnp[c + 2], s3 = bnp[c + 3];
                float h0 = bnp[128 + c], h1 = bnp[128 + c + 1], h2 = bnp[128 + c + 2], h3 = bnp[128 + c + 3];
                v.x = fmaf(v.x, s0, h0); v.y = fmaf(v.y, s1, h1);
                v.z = fmaf(v.z, s2, h2); v.w = fmaf(v.w, s3, h3);
                v.x = v.x >= 0.f ? v.x : alpha * v.x;
                v.y = v.y >= 0.f ? v.y : alpha * v.y;
                v.z = v.z >= 0.f ? v.z : alpha * v.z;
                v.w = v.w >= 0.f ? v.w : alpha * v.w;
            }
            As[c4 + 0][r] = v.x; As[c4 + 1][r] = v.y;
            As[c4 + 2][r] = v.z; As[c4 + 3][r] = v.w;
        }
        // B tile: 16 rows x 128 cols
#pragma unroll
        for (int l = 0; l < 2; l++) {
            int idx = tid + l * 256;
            int r = idx >> 5;
            int c4 = (idx & 31) << 2;
            float4 v = *(const float4*)(W + (size_t)(k0 + r) * OUT_DIM + c4);
            *(float4*)&Bs[r][c4] = v;
        }
        __syncthreads();
#pragma unroll
        for (int kk = 0; kk < 16; ++kk) {
            float4 a0 = *(const float4*)&As[kk][ty * 8];
            float4 a1 = *(const float4*)&As[kk][ty * 8 + 4];
            float4 b0 = *(const float4*)&Bs[kk][tx * 8];
            float4 b1 = *(const float4*)&Bs[kk][tx * 8 + 4];
            float a[8] = {a0.x, a0.y, a0.z, a0.w, a1.x, a1.y, a1.z, a1.w};
            float b[8] = {b0.x, b0.y, b0.z, b0.w, b1.x, b1.y, b1.z, b1.w};
#pragma unroll
            for (int i = 0; i < 8; i++)
#pragma unroll
                for (int j = 0; j < 8; j++)
                    acc[i][j] = fmaf(a[i], b[j], acc[i][j]);
        }
        __syncthreads();
    }
#pragma unroll
    for (int i = 0; i < 8; i++) {
        int r = row0 + ty * 8 + i;
        if (r < M) {
            float4 o0 = make_float4(acc[i][0], acc[i][1], acc[i][2], acc[i][3]);
            float4 o1 = make_float4(acc[i][4], acc[i][5], acc[i][6], acc[i][7]);
            *(float4*)(out + (size_t)r * OUT_DIM + tx * 8)     = o0;
            *(float4*)(out + (size_t)r * OUT_DIM + tx * 8 + 4) = o1;
        }
    }
}

// ---------------- Aggregation (1 wave per node, float2 per lane) ----------------

template <int STATS>
__global__ __launch_bounds__(256) void agg_kernel(
        const float* __restrict__ h, const int* __restrict__ rowp,
        const int* __restrict__ col, const float* __restrict__ dinv,
        const float* __restrict__ bias, float* __restrict__ out,
        float* __restrict__ stats, int n) {
    const int wave = threadIdx.x >> 6;
    const int lane = threadIdx.x & 63;
    const int f = lane << 1;
    const float b0 = bias[f], b1 = bias[f + 1];
    float s0 = 0.f, s1 = 0.f, q0 = 0.f, q1 = 0.f;
    for (int node = (blockIdx.x << 2) + wave; node < n; node += (gridDim.x << 2)) {
        int beg = rowp[node];
        int end = rowp[node + 1];
        float a0 = 0.f, a1 = 0.f;
        for (int e = beg; e < end; ++e) {
            int src = col[e];
            float w = dinv[src];
            float2 hv = *(const float2*)(h + (size_t)src * OUT_DIM + f);
            a0 = fmaf(w, hv.x, a0);
            a1 = fmaf(w, hv.y, a1);
        }
        float dn = dinv[node];
        a0 = fmaf(a0, dn, b0);
        a1 = fmaf(a1, dn, b1);
        *(float2*)(out + (size_t)node * OUT_DIM + f) = make_float2(a0, a1);
        if (STATS) { s0 += a0; s1 += a1; q0 = fmaf(a0, a0, q0); q1 = fmaf(a1, a1, q1); }
    }
    if (STATS) {
        __shared__ float red[4][256];
        red[wave][f] = s0;        red[wave][f + 1] = s1;
        red[wave][128 + f] = q0;  red[wave][128 + f + 1] = q1;
        __syncthreads();
        int t = threadIdx.x;
        float v = red[0][t] + red[1][t] + red[2][t] + red[3][t];
        atomicAdd(&stats[t], v);
    }
}

__global__ void bn_finalize(const float* __restrict__ stats, const float* __restrict__ g,
                            const float* __restrict__ be, float* __restrict__ bnp, float inv_n) {
    int f = threadIdx.x;  // 128
    float mean = stats[f] * inv_n;
    float var = stats[128 + f] * inv_n - mean * mean;
    var = fmaxf(var, 0.f);
    float sc = g[f] * rsqrtf(var + BN_EPS);
    bnp[f] = sc;
    bnp[128 + f] = be[f] - mean * sc;
}

// ---------------- launch ----------------

extern "C" void kernel_launch(void* const* d_in, const int* in_sizes, int n_in,
                              void* d_out, int out_size, void* d_ws, size_t ws_size,
                              hipStream_t stream) {
    const float* x   = (const float*)d_in[0];
    const int*   ei  = (const int*)d_in[1];
    const float* W1  = (const float*)d_in[2];
    const float* b1  = (const float*)d_in[3];
    const float* W2  = (const float*)d_in[4];
    const float* b2  = (const float*)d_in[5];
    const float* W3  = (const float*)d_in[6];
    const float* b3  = (const float*)d_in[7];
    const float* g1  = (const float*)d_in[8];
    const float* be1 = (const float*)d_in[9];
    const float* g2  = (const float*)d_in[10];
    const float* be2 = (const float*)d_in[11];
    const float* a1  = (const float*)d_in[12];
    const float* a2  = (const float*)d_in[13];

    const int n = N_NODES;
    const int E = in_sizes[1] / 2;
    float* out = (float*)d_out;

    char* ws = (char*)d_ws;
    size_t off = 0;
    auto alloc = [&](size_t bytes) { void* p = ws + off; off += (bytes + 255) & ~(size_t)255; return p; };
    float* bufA  = (float*)alloc((size_t)n * OUT_DIM * sizeof(float));
    int*   cnt   = (int*)alloc((size_t)n * sizeof(int));
    int*   rowp  = (int*)alloc((size_t)(n + 1) * sizeof(int));
    float* dinv  = (float*)alloc((size_t)n * sizeof(float));
    int*   col   = (int*)alloc((size_t)(E + n) * sizeof(int));
    float* stats = (float*)alloc(512 * sizeof(float));
    float* bnp1  = (float*)alloc(256 * sizeof(float));
    float* bnp2  = (float*)alloc(256 * sizeof(float));

    hipLaunchKernelGGL(init_kernel, dim3((n + 255) / 256), dim3(256), 0, stream, cnt, stats, n);
    hipLaunchKernelGGL(deg_kernel, dim3((E + 255) / 256), dim3(256), 0, stream, ei, cnt, E);
    hipLaunchKernelGGL(scan_kernel, dim3(1), dim3(1024), 0, stream, cnt, rowp, n);
    hipLaunchKernelGGL(selfloop_kernel, dim3((n + 255) / 256), dim3(256), 0, stream, cnt, rowp, dinv, col, n);
    hipLaunchKernelGGL(fill_kernel, dim3((E + 255) / 256), dim3(256), 0, stream, ei, cnt, col, E);

    const int gblocks = (n + 127) / 128;
    // layer 1
    hipLaunchKernelGGL((gemm_kernel<IN_DIM, false>), dim3(gblocks), dim3(256), 0, stream,
                       x, W1, bufA, n, nullptr, nullptr);
    hipLaunchKernelGGL((agg_kernel<1>), dim3(512), dim3(256), 0, stream,
                       bufA, rowp, col, dinv, b1, out, stats, n);
    hipLaunchKernelGGL(bn_finalize, dim3(1), dim3(128), 0, stream, stats, g1, be1, bnp1, 1.0f / n);
    // layer 2
    hipLaunchKernelGGL((gemm_kernel<OUT_DIM, true>), dim3(gblocks), dim3(256), 0, stream,
                       out, W2, bufA, n, bnp1, a1);
    hipLaunchKernelGGL((agg_kernel<1>), dim3(512), dim3(256), 0, stream,
                       bufA, rowp, col, dinv, b2, out, stats + 256, n);
    hipLaunchKernelGGL(bn_finalize, dim3(1), dim3(128), 0, stream, stats + 256, g2, be2, bnp2, 1.0f / n);
    // layer 3
    hipLaunchKernelGGL((gemm_kernel<OUT_DIM, true>), dim3(gblocks), dim3(256), 0, stream,
                       out, W3, bufA, n, bnp2, a2);
    hipLaunchKernelGGL((agg_kernel<0>), dim3(512), dim3(256), 0, stream,
                       bufA, rowp, col, dinv, b3, out, nullptr, n);
}

// Round 2
// 544.547 us; speedup vs baseline: 1.9317x; 1.9317x over previous
//
#include <hip/hip_runtime.h>

#define N_NODES 50000
#define IN_DIM  512
#define OUT_DIM 128
#define BN_EPS  1e-5f

// ---------------- CSR build ----------------

__global__ void init_kernel(int* __restrict__ cnt, float* __restrict__ stats, int n) {
    int i = blockIdx.x * blockDim.x + threadIdx.x;
    if (i < n) cnt[i] = 1;            // self-loop contributes 1 to every in-degree
    if (i < 512) stats[i] = 0.f;      // zero BN stat accumulators (both layers)
}

// Detect whether edge_index arrived as int64 (viewed as int32 pairs) or int32.
// Values are < 50000, so in int64 mode the odd int32 slots are all zero.
__device__ __forceinline__ int edge_is64(const int* ei) {
    return (ei[1] | ei[3] | ei[5] | ei[7]) == 0;
}

__global__ void deg_kernel(const int* __restrict__ ei, int* __restrict__ cnt, int E) {
    int e = blockIdx.x * blockDim.x + threadIdx.x;
    if (e >= E) return;
    int is64 = edge_is64(ei);
    int dst = is64 ? ei[2 * E + 2 * e] : ei[E + e];
    atomicAdd(&cnt[dst], 1);
}

// Single-block exclusive scan of cnt[0..n) -> rowp[0..n]; shfl-based wave scan.
__global__ __launch_bounds__(1024) void scan_kernel(const int* __restrict__ cnt,
                                                    int* __restrict__ rowp, int n) {
    __shared__ int wsum[16];
    __shared__ int chunk_base;
    const int tid = threadIdx.x;
    const int lane = tid & 63;
    const int wv = tid >> 6;
    if (tid == 0) chunk_base = 0;
    __syncthreads();
    for (int base = 0; base < n + 1023; base += 1024) {
        int i = base + tid;
        int orig = (i < n) ? cnt[i] : 0;
        int v = orig;
#pragma unroll
        for (int d = 1; d < 64; d <<= 1) {
            int t = __shfl_up(v, d);
            if (lane >= d) v += t;
        }
        if (lane == 63) wsum[wv] = v;
        __syncthreads();                       // wsum ready; prev chunk_base visible
        int woff = 0;
        for (int w = 0; w < wv; ++w) woff += wsum[w];
        int cb = chunk_base;
        if (i < n) rowp[i] = cb + woff + v - orig;
        int newbase = cb + woff + v;           // tid 1023: full chunk total
        __syncthreads();                       // all reads of chunk_base/wsum done
        if (tid == 1023) chunk_base = newbase;
        __syncthreads();
    }
    if (tid == 0) rowp[n] = chunk_base;
}

// dinv, write self-loop entry, init fill cursor (reuses cnt)
__global__ void selfloop_kernel(int* __restrict__ cnt, const int* __restrict__ rowp,
                                float* __restrict__ dinv, int* __restrict__ col, int n) {
    int i = blockIdx.x * blockDim.x + threadIdx.x;
    if (i >= n) return;
    int deg = cnt[i];
    dinv[i] = rsqrtf(fmaxf((float)deg, 1.f));
    int rp = rowp[i];
    col[rp] = i;          // self loop first
    cnt[i] = rp + 1;      // cursor for edge fill
}

__global__ void fill_kernel(const int* __restrict__ ei, int* __restrict__ cnt,
                            int* __restrict__ col, int E) {
    int e = blockIdx.x * blockDim.x + threadIdx.x;
    if (e >= E) return;
    int is64 = edge_is64(ei);
    int src, dst;
    if (is64) { src = ei[2 * e];     dst = ei[2 * E + 2 * e]; }
    else      { src = ei[e];         dst = ei[E + e]; }
    int pos = atomicAdd(&cnt[dst], 1);
    col[pos] = src;
}

// ---------------- GEMM (fp32, 128x128 tile, 8x8 per thread) ----------------
// XFORM: apply per-column BN scale/shift + PReLU to A elements on load.
// Epilogue pre-scales each output row by dinv[row] (folds the per-edge
// dinv[src] factor of GCN aggregation into the producer).

template <int K, bool XFORM>
__global__ __launch_bounds__(256) void gemm_kernel(
        const float* __restrict__ A, const float* __restrict__ W,
        float* __restrict__ out, int M,
        const float* __restrict__ bnp, const float* __restrict__ alpha_p,
        const float* __restrict__ dinv) {
    __shared__ float As[16][132];   // A^T tile: [k][m]
    __shared__ float Bs[16][132];   // B tile:   [k][nout]
    const int tid = threadIdx.x;
    const int tx = tid & 15;
    const int ty = tid >> 4;
    const int row0 = blockIdx.x * 128;
    float alpha = 0.f;
    if (XFORM) alpha = alpha_p[0];

    float acc[8][8];
#pragma unroll
    for (int i = 0; i < 8; i++)
#pragma unroll
        for (int j = 0; j < 8; j++) acc[i][j] = 0.f;

    for (int k0 = 0; k0 < K; k0 += 16) {
#pragma unroll
        for (int l = 0; l < 2; l++) {
            int idx = tid + l * 256;
            int r = idx >> 2;
            int c4 = (idx & 3) << 2;
            int gr = row0 + r;
            float4 v = make_float4(0.f, 0.f, 0.f, 0.f);
            if (gr < M) v = *(const float4*)(A + (size_t)gr * K + (k0 + c4));
            if (XFORM) {
                int c = k0 + c4;
                float s0 = bnp[c], s1 = bnp[c + 1], s2 = bnp[c + 2], s3 = bnp[c + 3];
                float h0 = bnp[128 + c], h1 = bnp[128 + c + 1], h2 = bnp[128 + c + 2], h3 = bnp[128 + c + 3];
                v.x = fmaf(v.x, s0, h0); v.y = fmaf(v.y, s1, h1);
                v.z = fmaf(v.z, s2, h2); v.w = fmaf(v.w, s3, h3);
                v.x = v.x >= 0.f ? v.x : alpha * v.x;
                v.y = v.y >= 0.f ? v.y : alpha * v.y;
                v.z = v.z >= 0.f ? v.z : alpha * v.z;
                v.w = v.w >= 0.f ? v.w : alpha * v.w;
            }
            As[c4 + 0][r] = v.x; As[c4 + 1][r] = v.y;
            As[c4 + 2][r] = v.z; As[c4 + 3][r] = v.w;
        }
#pragma unroll
        for (int l = 0; l < 2; l++) {
            int idx = tid + l * 256;
            int r = idx >> 5;
            int c4 = (idx & 31) << 2;
            float4 v = *(const float4*)(W + (size_t)(k0 + r) * OUT_DIM + c4);
            *(float4*)&Bs[r][c4] = v;
        }
        __syncthreads();
#pragma unroll
        for (int kk = 0; kk < 16; ++kk) {
            float4 a0 = *(const float4*)&As[kk][ty * 8];
            float4 a1 = *(const float4*)&As[kk][ty * 8 + 4];
            float4 b0 = *(const float4*)&Bs[kk][tx * 8];
            float4 b1 = *(const float4*)&Bs[kk][tx * 8 + 4];
            float a[8] = {a0.x, a0.y, a0.z, a0.w, a1.x, a1.y, a1.z, a1.w};
            float b[8] = {b0.x, b0.y, b0.z, b0.w, b1.x, b1.y, b1.z, b1.w};
#pragma unroll
            for (int i = 0; i < 8; i++)
#pragma unroll
                for (int j = 0; j < 8; j++)
                    acc[i][j] = fmaf(a[i], b[j], acc[i][j]);
        }
        __syncthreads();
    }
#pragma unroll
    for (int i = 0; i < 8; i++) {
        int r = row0 + ty * 8 + i;
        if (r < M) {
            float dv = dinv[r];
            float4 o0 = make_float4(acc[i][0] * dv, acc[i][1] * dv, acc[i][2] * dv, acc[i][3] * dv);
            float4 o1 = make_float4(acc[i][4] * dv, acc[i][5] * dv, acc[i][6] * dv, acc[i][7] * dv);
            *(float4*)(out + (size_t)r * OUT_DIM + tx * 8)     = o0;
            *(float4*)(out + (size_t)r * OUT_DIM + tx * 8 + 4) = o1;
        }
    }
}

// ---------------- Aggregation (1 node per wave, float2 per lane) ----------------
// h rows arrive pre-scaled by dinv[src]; inner loop is pure adds with 4
// independent gather chains.

__global__ __launch_bounds__(256) void agg_kernel(
        const float* __restrict__ h, const int* __restrict__ rowp,
        const int* __restrict__ col, const float* __restrict__ dinv,
        const float* __restrict__ bias, float* __restrict__ out, int n) {
    const int wave = threadIdx.x >> 6;
    const int lane = threadIdx.x & 63;
    const int node = (blockIdx.x << 2) + wave;
    if (node >= n) return;
    const int f = lane << 1;
    int e = rowp[node];
    const int end = rowp[node + 1];
    float a0 = 0.f, a1 = 0.f;
    for (; e + 4 <= end; e += 4) {
        int c0 = col[e], c1 = col[e + 1], c2 = col[e + 2], c3 = col[e + 3];
        float2 h0 = *(const float2*)(h + (size_t)c0 * OUT_DIM + f);
        float2 h1 = *(const float2*)(h + (size_t)c1 * OUT_DIM + f);
        float2 h2 = *(const float2*)(h + (size_t)c2 * OUT_DIM + f);
        float2 h3 = *(const float2*)(h + (size_t)c3 * OUT_DIM + f);
        a0 += (h0.x + h1.x) + (h2.x + h3.x);
        a1 += (h0.y + h1.y) + (h2.y + h3.y);
    }
    for (; e < end; ++e) {
        int s = col[e];
        float2 hv = *(const float2*)(h + (size_t)s * OUT_DIM + f);
        a0 += hv.x; a1 += hv.y;
    }
    float dn = dinv[node];
    a0 = fmaf(a0, dn, bias[f]);
    a1 = fmaf(a1, dn, bias[f + 1]);
    *(float2*)(out + (size_t)node * OUT_DIM + f) = make_float2(a0, a1);
}

// ---------------- BN stats over agg output ----------------

__global__ __launch_bounds__(256) void bn_stats(const float* __restrict__ out,
                                                float* __restrict__ stats, int n) {
    const int wave = threadIdx.x >> 6;
    const int lane = threadIdx.x & 63;
    const int f = lane << 1;
    float s0 = 0.f, s1 = 0.f, q0 = 0.f, q1 = 0.f;
    for (int node = (blockIdx.x << 2) + wave; node < n; node += (gridDim.x << 2)) {
        float2 v = *(const float2*)(out + (size_t)node * OUT_DIM + f);
        s0 += v.x; s1 += v.y;
        q0 = fmaf(v.x, v.x, q0); q1 = fmaf(v.y, v.y, q1);
    }
    __shared__ float red[4][256];
    red[wave][f] = s0;        red[wave][f + 1] = s1;
    red[wave][128 + f] = q0;  red[wave][128 + f + 1] = q1;
    __syncthreads();
    int t = threadIdx.x;
    float v = red[0][t] + red[1][t] + red[2][t] + red[3][t];
    atomicAdd(&stats[t], v);
}

__global__ void bn_finalize(const float* __restrict__ stats, const float* __restrict__ g,
                            const float* __restrict__ be, float* __restrict__ bnp, float inv_n) {
    int f = threadIdx.x;  // 128
    float mean = stats[f] * inv_n;
    float var = stats[128 + f] * inv_n - mean * mean;
    var = fmaxf(var, 0.f);
    float sc = g[f] * rsqrtf(var + BN_EPS);
    bnp[f] = sc;
    bnp[128 + f] = be[f] - mean * sc;
}

// ---------------- launch ----------------

extern "C" void kernel_launch(void* const* d_in, const int* in_sizes, int n_in,
                              void* d_out, int out_size, void* d_ws, size_t ws_size,
                              hipStream_t stream) {
    const float* x   = (const float*)d_in[0];
    const int*   ei  = (const int*)d_in[1];
    const float* W1  = (const float*)d_in[2];
    const float* b1  = (const float*)d_in[3];
    const float* W2  = (const float*)d_in[4];
    const float* b2  = (const float*)d_in[5];
    const float* W3  = (const float*)d_in[6];
    const float* b3  = (const float*)d_in[7];
    const float* g1  = (const float*)d_in[8];
    const float* be1 = (const float*)d_in[9];
    const float* g2  = (const float*)d_in[10];
    const float* be2 = (const float*)d_in[11];
    const float* a1  = (const float*)d_in[12];
    const float* a2  = (const float*)d_in[13];

    const int n = N_NODES;
    const int E = in_sizes[1] / 2;
    float* out = (float*)d_out;

    char* ws = (char*)d_ws;
    size_t off = 0;
    auto alloc = [&](size_t bytes) { void* p = ws + off; off += (bytes + 255) & ~(size_t)255; return p; };
    float* bufA  = (float*)alloc((size_t)n * OUT_DIM * sizeof(float));
    int*   cnt   = (int*)alloc((size_t)n * sizeof(int));
    int*   rowp  = (int*)alloc((size_t)(n + 1) * sizeof(int));
    float* dinv  = (float*)alloc((size_t)n * sizeof(float));
    int*   col   = (int*)alloc((size_t)(E + n) * sizeof(int));
    float* stats = (float*)alloc(512 * sizeof(float));
    float* bnp1  = (float*)alloc(256 * sizeof(float));
    float* bnp2  = (float*)alloc(256 * sizeof(float));

    hipLaunchKernelGGL(init_kernel, dim3((n + 255) / 256), dim3(256), 0, stream, cnt, stats, n);
    hipLaunchKernelGGL(deg_kernel, dim3((E + 255) / 256), dim3(256), 0, stream, ei, cnt, E);
    hipLaunchKernelGGL(scan_kernel, dim3(1), dim3(1024), 0, stream, cnt, rowp, n);
    hipLaunchKernelGGL(selfloop_kernel, dim3((n + 255) / 256), dim3(256), 0, stream, cnt, rowp, dinv, col, n);
    hipLaunchKernelGGL(fill_kernel, dim3((E + 255) / 256), dim3(256), 0, stream, ei, cnt, col, E);

    const int gblocks = (n + 127) / 128;
    const int ablocks = (n + 3) / 4;          // one node per wave
    // layer 1
    hipLaunchKernelGGL((gemm_kernel<IN_DIM, false>), dim3(gblocks), dim3(256), 0, stream,
                       x, W1, bufA, n, nullptr, nullptr, dinv);
    hipLaunchKernelGGL(agg_kernel, dim3(ablocks), dim3(256), 0, stream,
                       bufA, rowp, col, dinv, b1, out, n);
    hipLaunchKernelGGL(bn_stats, dim3(256), dim3(256), 0, stream, out, stats, n);
    hipLaunchKernelGGL(bn_finalize, dim3(1), dim3(128), 0, stream, stats, g1, be1, bnp1, 1.0f / n);
    // layer 2
    hipLaunchKernelGGL((gemm_kernel<OUT_DIM, true>), dim3(gblocks), dim3(256), 0, stream,
                       out, W2, bufA, n, bnp1, a1, dinv);
    hipLaunchKernelGGL(agg_kernel, dim3(ablocks), dim3(256), 0, stream,
                       bufA, rowp, col, dinv, b2, out, n);
    hipLaunchKernelGGL(bn_stats, dim3(256), dim3(256), 0, stream, out, stats + 256, n);
    hipLaunchKernelGGL(bn_finalize, dim3(1), dim3(128), 0, stream, stats + 256, g2, be2, bnp2, 1.0f / n);
    // layer 3
    hipLaunchKernelGGL((gemm_kernel<OUT_DIM, true>), dim3(gblocks), dim3(256), 0, stream,
                       out, W3, bufA, n, bnp2, a2, dinv);
    hipLaunchKernelGGL(agg_kernel, dim3(ablocks), dim3(256), 0, stream,
                       bufA, rowp, col, dinv, b3, out, n);
}

// Round 3
// 505.827 us; speedup vs baseline: 2.0796x; 1.0765x over previous
//
#include <hip/hip_runtime.h>

#define N_NODES 50000
#define IN_DIM  512
#define OUT_DIM 128
#define BN_EPS  1e-5f

typedef __attribute__((ext_vector_type(8))) short short8;
typedef __attribute__((ext_vector_type(4))) float f32x4;

__device__ __forceinline__ short bf16_rne(float x) {
    unsigned u = __float_as_uint(x);
    unsigned r = (u + 0x7FFFu + ((u >> 16) & 1u)) >> 16;
    return (short)r;
}

// ---------------- CSR build ----------------

__global__ void init_kernel(int* __restrict__ cnt, float* __restrict__ stats, int n) {
    int i = blockIdx.x * blockDim.x + threadIdx.x;
    if (i < n) cnt[i] = 1;            // self-loop contributes 1 to every in-degree
    if (i < 512) stats[i] = 0.f;      // zero BN stat accumulators (both layers)
}

// Detect whether edge_index arrived as int64 (viewed as int32 pairs) or int32.
__device__ __forceinline__ int edge_is64(const int* ei) {
    return (ei[1] | ei[3] | ei[5] | ei[7]) == 0;
}

__global__ void deg_kernel(const int* __restrict__ ei, int* __restrict__ cnt, int E) {
    int e = blockIdx.x * blockDim.x + threadIdx.x;
    if (e >= E) return;
    int is64 = edge_is64(ei);
    int dst = is64 ? ei[2 * E + 2 * e] : ei[E + e];
    atomicAdd(&cnt[dst], 1);
}

// Single-block exclusive scan of cnt[0..n) -> rowp[0..n]; shfl-based wave scan.
__global__ __launch_bounds__(1024) void scan_kernel(const int* __restrict__ cnt,
                                                    int* __restrict__ rowp, int n) {
    __shared__ int wsum[16];
    __shared__ int chunk_base;
    const int tid = threadIdx.x;
    const int lane = tid & 63;
    const int wv = tid >> 6;
    if (tid == 0) chunk_base = 0;
    __syncthreads();
    for (int base = 0; base < n + 1023; base += 1024) {
        int i = base + tid;
        int orig = (i < n) ? cnt[i] : 0;
        int v = orig;
#pragma unroll
        for (int d = 1; d < 64; d <<= 1) {
            int t = __shfl_up(v, d);
            if (lane >= d) v += t;
        }
        if (lane == 63) wsum[wv] = v;
        __syncthreads();
        int woff = 0;
        for (int w = 0; w < wv; ++w) woff += wsum[w];
        int cb = chunk_base;
        if (i < n) rowp[i] = cb + woff + v - orig;
        int newbase = cb + woff + v;
        __syncthreads();
        if (tid == 1023) chunk_base = newbase;
        __syncthreads();
    }
    if (tid == 0) rowp[n] = chunk_base;
}

__global__ void selfloop_kernel(int* __restrict__ cnt, const int* __restrict__ rowp,
                                float* __restrict__ dinv, int* __restrict__ col, int n) {
    int i = blockIdx.x * blockDim.x + threadIdx.x;
    if (i >= n) return;
    int deg = cnt[i];
    dinv[i] = rsqrtf(fmaxf((float)deg, 1.f));
    int rp = rowp[i];
    col[rp] = i;          // self loop first
    cnt[i] = rp + 1;      // cursor for edge fill
}

__global__ void fill_kernel(const int* __restrict__ ei, int* __restrict__ cnt,
                            int* __restrict__ col, int E) {
    int e = blockIdx.x * blockDim.x + threadIdx.x;
    if (e >= E) return;
    int is64 = edge_is64(ei);
    int src, dst;
    if (is64) { src = ei[2 * e];     dst = ei[2 * E + 2 * e]; }
    else      { src = ei[e];         dst = ei[E + e]; }
    int pos = atomicAdd(&cnt[dst], 1);
    col[pos] = src;
}

// ---------------- W convert+transpose: [K][128] fp32 -> [128][K] bf16 ----------------

__global__ __launch_bounds__(256) void wconv_kernel(const float* __restrict__ W,
                                                    short* __restrict__ Wt, int K) {
    __shared__ short tile[64][130];
    const int k0 = blockIdx.x * 64;
    for (int i = threadIdx.x; i < 64 * 128; i += 256) {
        int k = i >> 7, c = i & 127;
        tile[k][c] = bf16_rne(W[(size_t)(k0 + k) * 128 + c]);
    }
    __syncthreads();
    for (int i = threadIdx.x; i < 64 * 128; i += 256) {
        int c = i >> 6, k = i & 63;
        Wt[(size_t)c * K + k0 + k] = tile[k][c];
    }
}

// ---------------- MFMA GEMM (bf16 in, fp32 acc), LDS-free ----------------
// Wave w of 4 owns 16 rows x 128 cols. A fp32->bf16 on load; B from bf16
// col-major Wt (L2-resident). Self-consistent k-map: k = (lane>>4)*8 + j for
// both A and B frags. C/D: col=lane&15, row=(lane>>4)*4+reg (verified layout).
// XFORM applies BN scale/shift + PReLU to A on load. Epilogue scales each
// output row by dinv[row].

template <int K, bool XFORM>
__global__ __launch_bounds__(256) void mfma_gemm(
        const float* __restrict__ A, const short* __restrict__ Wt,
        float* __restrict__ out, int M,
        const float* __restrict__ bnp, const float* __restrict__ alpha_p,
        const float* __restrict__ dinv) {
    const int lane = threadIdx.x & 63;
    const int wv   = threadIdx.x >> 6;
    const int row0 = blockIdx.x * 64 + wv * 16;
    const int r16  = lane & 15;
    const int g    = lane >> 4;
    float alpha = 0.f;
    if (XFORM) alpha = alpha_p[0];

    f32x4 acc[8];
#pragma unroll
    for (int nf = 0; nf < 8; nf++) acc[nf] = (f32x4)(0.f);

    int arow = row0 + r16;
    if (arow >= M) arow = M - 1;          // clamp; stores are guarded
    const float* Arow = A + (size_t)arow * K;

    for (int k0 = 0; k0 < K; k0 += 32) {
        const int kk = k0 + g * 8;
        float4 a0 = *(const float4*)(Arow + kk);
        float4 a1 = *(const float4*)(Arow + kk + 4);
        float av[8] = {a0.x, a0.y, a0.z, a0.w, a1.x, a1.y, a1.z, a1.w};
        if (XFORM) {
#pragma unroll
            for (int j = 0; j < 8; j++) {
                float v = fmaf(av[j], bnp[kk + j], bnp[128 + kk + j]);
                av[j] = v >= 0.f ? v : alpha * v;
            }
        }
        short8 afrag;
#pragma unroll
        for (int j = 0; j < 8; j++) afrag[j] = bf16_rne(av[j]);
#pragma unroll
        for (int nf = 0; nf < 8; nf++) {
            const int colb = nf * 16 + r16;
            short8 bfrag = *(const short8*)(Wt + (size_t)colb * K + kk);
            acc[nf] = __builtin_amdgcn_mfma_f32_16x16x32_bf16(afrag, bfrag, acc[nf], 0, 0, 0);
        }
    }
#pragma unroll
    for (int r = 0; r < 4; r++) {
        const int row = row0 + g * 4 + r;
        if (row < M) {
            const float dv = dinv[row];
#pragma unroll
            for (int nf = 0; nf < 8; nf++) {
                out[(size_t)row * OUT_DIM + nf * 16 + r16] = acc[nf][r] * dv;
            }
        }
    }
}

// ---------------- Aggregation (1 node per wave, float2 per lane) ----------------

__global__ __launch_bounds__(256) void agg_kernel(
        const float* __restrict__ h, const int* __restrict__ rowp,
        const int* __restrict__ col, const float* __restrict__ dinv,
        const float* __restrict__ bias, float* __restrict__ out, int n) {
    const int wave = threadIdx.x >> 6;
    const int lane = threadIdx.x & 63;
    const int node = (blockIdx.x << 2) + wave;
    if (node >= n) return;
    const int f = lane << 1;
    int e = rowp[node];
    const int end = rowp[node + 1];
    float a0 = 0.f, a1 = 0.f;
    for (; e + 4 <= end; e += 4) {
        int c0 = col[e], c1 = col[e + 1], c2 = col[e + 2], c3 = col[e + 3];
        float2 h0 = *(const float2*)(h + (size_t)c0 * OUT_DIM + f);
        float2 h1 = *(const float2*)(h + (size_t)c1 * OUT_DIM + f);
        float2 h2 = *(const float2*)(h + (size_t)c2 * OUT_DIM + f);
        float2 h3 = *(const float2*)(h + (size_t)c3 * OUT_DIM + f);
        a0 += (h0.x + h1.x) + (h2.x + h3.x);
        a1 += (h0.y + h1.y) + (h2.y + h3.y);
    }
    for (; e < end; ++e) {
        int s = col[e];
        float2 hv = *(const float2*)(h + (size_t)s * OUT_DIM + f);
        a0 += hv.x; a1 += hv.y;
    }
    float dn = dinv[node];
    a0 = fmaf(a0, dn, bias[f]);
    a1 = fmaf(a1, dn, bias[f + 1]);
    *(float2*)(out + (size_t)node * OUT_DIM + f) = make_float2(a0, a1);
}

// ---------------- BN stats over agg output ----------------

__global__ __launch_bounds__(256) void bn_stats(const float* __restrict__ out,
                                                float* __restrict__ stats, int n) {
    const int wave = threadIdx.x >> 6;
    const int lane = threadIdx.x & 63;
    const int f = lane << 1;
    float s0 = 0.f, s1 = 0.f, q0 = 0.f, q1 = 0.f;
    for (int node = (blockIdx.x << 2) + wave; node < n; node += (gridDim.x << 2)) {
        float2 v = *(const float2*)(out + (size_t)node * OUT_DIM + f);
        s0 += v.x; s1 += v.y;
        q0 = fmaf(v.x, v.x, q0); q1 = fmaf(v.y, v.y, q1);
    }
    __shared__ float red[4][256];
    red[wave][f] = s0;        red[wave][f + 1] = s1;
    red[wave][128 + f] = q0;  red[wave][128 + f + 1] = q1;
    __syncthreads();
    int t = threadIdx.x;
    float v = red[0][t] + red[1][t] + red[2][t] + red[3][t];
    atomicAdd(&stats[t], v);
}

__global__ void bn_finalize(const float* __restrict__ stats, const float* __restrict__ g,
                            const float* __restrict__ be, float* __restrict__ bnp, float inv_n) {
    int f = threadIdx.x;  // 128
    float mean = stats[f] * inv_n;
    float var = stats[128 + f] * inv_n - mean * mean;
    var = fmaxf(var, 0.f);
    float sc = g[f] * rsqrtf(var + BN_EPS);
    bnp[f] = sc;
    bnp[128 + f] = be[f] - mean * sc;
}

// ---------------- launch ----------------

extern "C" void kernel_launch(void* const* d_in, const int* in_sizes, int n_in,
                              void* d_out, int out_size, void* d_ws, size_t ws_size,
                              hipStream_t stream) {
    const float* x   = (const float*)d_in[0];
    const int*   ei  = (const int*)d_in[1];
    const float* W1  = (const float*)d_in[2];
    const float* b1  = (const float*)d_in[3];
    const float* W2  = (const float*)d_in[4];
    const float* b2  = (const float*)d_in[5];
    const float* W3  = (const float*)d_in[6];
    const float* b3  = (const float*)d_in[7];
    const float* g1  = (const float*)d_in[8];
    const float* be1 = (const float*)d_in[9];
    const float* g2  = (const float*)d_in[10];
    const float* be2 = (const float*)d_in[11];
    const float* a1  = (const float*)d_in[12];
    const float* a2  = (const float*)d_in[13];

    const int n = N_NODES;
    const int E = in_sizes[1] / 2;
    float* out = (float*)d_out;

    char* ws = (char*)d_ws;
    size_t off = 0;
    auto alloc = [&](size_t bytes) { void* p = ws + off; off += (bytes + 255) & ~(size_t)255; return p; };
    float* bufA  = (float*)alloc((size_t)n * OUT_DIM * sizeof(float));
    int*   cnt   = (int*)alloc((size_t)n * sizeof(int));
    int*   rowp  = (int*)alloc((size_t)(n + 1) * sizeof(int));
    float* dinv  = (float*)alloc((size_t)n * sizeof(float));
    int*   col   = (int*)alloc((size_t)(E + n) * sizeof(int));
    float* stats = (float*)alloc(512 * sizeof(float));
    float* bnp1  = (float*)alloc(256 * sizeof(float));
    float* bnp2  = (float*)alloc(256 * sizeof(float));
    short* Wt1   = (short*)alloc((size_t)IN_DIM * OUT_DIM * sizeof(short));
    short* Wt2   = (short*)alloc((size_t)OUT_DIM * OUT_DIM * sizeof(short));
    short* Wt3   = (short*)alloc((size_t)OUT_DIM * OUT_DIM * sizeof(short));

    hipLaunchKernelGGL(init_kernel, dim3((n + 255) / 256), dim3(256), 0, stream, cnt, stats, n);
    hipLaunchKernelGGL(deg_kernel, dim3((E + 255) / 256), dim3(256), 0, stream, ei, cnt, E);
    hipLaunchKernelGGL(scan_kernel, dim3(1), dim3(1024), 0, stream, cnt, rowp, n);
    hipLaunchKernelGGL(selfloop_kernel, dim3((n + 255) / 256), dim3(256), 0, stream, cnt, rowp, dinv, col, n);
    hipLaunchKernelGGL(fill_kernel, dim3((E + 255) / 256), dim3(256), 0, stream, ei, cnt, col, E);
    hipLaunchKernelGGL(wconv_kernel, dim3(IN_DIM / 64), dim3(256), 0, stream, W1, Wt1, IN_DIM);
    hipLaunchKernelGGL(wconv_kernel, dim3(OUT_DIM / 64), dim3(256), 0, stream, W2, Wt2, OUT_DIM);
    hipLaunchKernelGGL(wconv_kernel, dim3(OUT_DIM / 64), dim3(256), 0, stream, W3, Wt3, OUT_DIM);

    const int gblocks = (n + 63) / 64;        // 64 rows per block (4 waves x 16)
    const int ablocks = (n + 3) / 4;          // one node per wave
    // layer 1
    hipLaunchKernelGGL((mfma_gemm<IN_DIM, false>), dim3(gblocks), dim3(256), 0, stream,
                       x, Wt1, bufA, n, nullptr, nullptr, dinv);
    hipLaunchKernelGGL(agg_kernel, dim3(ablocks), dim3(256), 0, stream,
                       bufA, rowp, col, dinv, b1, out, n);
    hipLaunchKernelGGL(bn_stats, dim3(256), dim3(256), 0, stream, out, stats, n);
    hipLaunchKernelGGL(bn_finalize, dim3(1), dim3(128), 0, stream, stats, g1, be1, bnp1, 1.0f / n);
    // layer 2
    hipLaunchKernelGGL((mfma_gemm<OUT_DIM, true>), dim3(gblocks), dim3(256), 0, stream,
                       out, Wt2, bufA, n, bnp1, a1, dinv);
    hipLaunchKernelGGL(agg_kernel, dim3(ablocks), dim3(256), 0, stream,
                       bufA, rowp, col, dinv, b2, out, n);
    hipLaunchKernelGGL(bn_stats, dim3(256), dim3(256), 0, stream, out, stats + 256, n);
    hipLaunchKernelGGL(bn_finalize, dim3(1), dim3(128), 0, stream, stats + 256, g2, be2, bnp2, 1.0f / n);
    // layer 3
    hipLaunchKernelGGL((mfma_gemm<OUT_DIM, true>), dim3(gblocks), dim3(256), 0, stream,
                       out, Wt3, bufA, n, bnp2, a2, dinv);
    hipLaunchKernelGGL(agg_kernel, dim3(ablocks), dim3(256), 0, stream,
                       bufA, rowp, col, dinv, b3, out, n);
}

// Round 4
// 500.751 us; speedup vs baseline: 2.1006x; 1.0101x over previous
//
#include <hip/hip_runtime.h>

#define N_NODES 50000
#define IN_DIM  512
#define OUT_DIM 128
#define BN_EPS  1e-5f

typedef __attribute__((ext_vector_type(8))) short short8;
typedef __attribute__((ext_vector_type(4))) float f32x4;

__device__ __forceinline__ short bf16_rne(float x) {
    unsigned u = __float_as_uint(x);
    unsigned r = (u + 0x7FFFu + ((u >> 16) & 1u)) >> 16;
    return (short)r;
}

// ---------------- CSR build ----------------

__global__ void init_kernel(int* __restrict__ cnt, float* __restrict__ stats, int n) {
    int i = blockIdx.x * blockDim.x + threadIdx.x;
    if (i < n) cnt[i] = 1;            // self-loop contributes 1 to every in-degree
    if (i < 512) stats[i] = 0.f;      // zero BN stat accumulators (both layers)
}

// Detect whether edge_index arrived as int64 (viewed as int32 pairs) or int32.
__device__ __forceinline__ int edge_is64(const int* ei) {
    return (ei[1] | ei[3] | ei[5] | ei[7]) == 0;
}

__global__ void deg_kernel(const int* __restrict__ ei, int* __restrict__ cnt, int E) {
    int e = blockIdx.x * blockDim.x + threadIdx.x;
    if (e >= E) return;
    int is64 = edge_is64(ei);
    int dst = is64 ? ei[2 * E + 2 * e] : ei[E + e];
    atomicAdd(&cnt[dst], 1);
}

// Single-block exclusive scan of cnt[0..n) -> rowp[0..n]; shfl-based wave scan.
__global__ __launch_bounds__(1024) void scan_kernel(const int* __restrict__ cnt,
                                                    int* __restrict__ rowp, int n) {
    __shared__ int wsum[16];
    __shared__ int chunk_base;
    const int tid = threadIdx.x;
    const int lane = tid & 63;
    const int wv = tid >> 6;
    if (tid == 0) chunk_base = 0;
    __syncthreads();
    for (int base = 0; base < n + 1023; base += 1024) {
        int i = base + tid;
        int orig = (i < n) ? cnt[i] : 0;
        int v = orig;
#pragma unroll
        for (int d = 1; d < 64; d <<= 1) {
            int t = __shfl_up(v, d);
            if (lane >= d) v += t;
        }
        if (lane == 63) wsum[wv] = v;
        __syncthreads();
        int woff = 0;
        for (int w = 0; w < wv; ++w) woff += wsum[w];
        int cb = chunk_base;
        if (i < n) rowp[i] = cb + woff + v - orig;
        int newbase = cb + woff + v;
        __syncthreads();
        if (tid == 1023) chunk_base = newbase;
        __syncthreads();
    }
    if (tid == 0) rowp[n] = chunk_base;
}

__global__ void selfloop_kernel(int* __restrict__ cnt, const int* __restrict__ rowp,
                                float* __restrict__ dinv, int* __restrict__ col, int n) {
    int i = blockIdx.x * blockDim.x + threadIdx.x;
    if (i >= n) return;
    int deg = cnt[i];
    dinv[i] = rsqrtf(fmaxf((float)deg, 1.f));
    int rp = rowp[i];
    col[rp] = i;          // self loop first
    cnt[i] = rp + 1;      // cursor for edge fill
}

__global__ void fill_kernel(const int* __restrict__ ei, int* __restrict__ cnt,
                            int* __restrict__ col, int E) {
    int e = blockIdx.x * blockDim.x + threadIdx.x;
    if (e >= E) return;
    int is64 = edge_is64(ei);
    int src, dst;
    if (is64) { src = ei[2 * e];     dst = ei[2 * E + 2 * e]; }
    else      { src = ei[e];         dst = ei[E + e]; }
    int pos = atomicAdd(&cnt[dst], 1);
    col[pos] = src;
}

// ---------------- W convert+transpose: [K][128] fp32 -> [128][K] bf16 ----------------

__global__ __launch_bounds__(256) void wconv_kernel(const float* __restrict__ W,
                                                    short* __restrict__ Wt, int K) {
    __shared__ short tile[64][130];
    const int k0 = blockIdx.x * 64;
    for (int i = threadIdx.x; i < 64 * 128; i += 256) {
        int k = i >> 7, c = i & 127;
        tile[k][c] = bf16_rne(W[(size_t)(k0 + k) * 128 + c]);
    }
    __syncthreads();
    for (int i = threadIdx.x; i < 64 * 128; i += 256) {
        int c = i >> 6, k = i & 63;
        Wt[(size_t)c * K + k0 + k] = tile[k][c];
    }
}

// ---------------- MFMA GEMM (bf16 in, fp32 acc), LDS-free, software-pipelined ----
// 2 waves/block, each wave owns 16 rows x 128 cols. A prefetched 2 k-steps
// ahead (HBM latency), B frags 1 step ahead (L2 latency). Self-consistent
// k-map: k = (lane>>4)*8 + j for both A and B. C/D: col=lane&15,
// row=(lane>>4)*4+reg. XFORM = BN+PReLU on A load; epilogue scales by dinv.

template <int K, bool XFORM>
__global__ __launch_bounds__(128) void mfma_gemm(
        const float* __restrict__ A, const short* __restrict__ Wt,
        float* __restrict__ out, int M,
        const float* __restrict__ bnp, const float* __restrict__ alpha_p,
        const float* __restrict__ dinv) {
    constexpr int NSTEP = K / 32;
    const int lane = threadIdx.x & 63;
    const int wv   = threadIdx.x >> 6;
    const int row0 = blockIdx.x * 32 + wv * 16;
    const int r16  = lane & 15;
    const int g    = lane >> 4;
    float alpha = 0.f;
    if (XFORM) alpha = alpha_p[0];

    f32x4 acc[8];
#pragma unroll
    for (int nf = 0; nf < 8; nf++) acc[nf] = (f32x4)(0.f);

    int arow = row0 + r16;
    if (arow >= M) arow = M - 1;          // clamp; stores are guarded
    const float* Arow = A + (size_t)arow * K + g * 8;       // + s*32 per step
    const short* Bbase = Wt + (size_t)r16 * K + g * 8;      // + nf*16*K + s*32

    // A pipeline depth 2 (rotating buffer), B depth 1 (ping-pong)
    float4 abuf[3][2];
    short8 cb[8], pb[8];

    abuf[0][0] = *(const float4*)(Arow);
    abuf[0][1] = *(const float4*)(Arow + 4);
    if (NSTEP > 1) {
        abuf[1][0] = *(const float4*)(Arow + 32);
        abuf[1][1] = *(const float4*)(Arow + 36);
    }
#pragma unroll
    for (int nf = 0; nf < 8; nf++)
        cb[nf] = *(const short8*)(Bbase + (size_t)nf * 16 * K);

#pragma unroll
    for (int s = 0; s < NSTEP; ++s) {
        if (s + 2 < NSTEP) {
            abuf[(s + 2) % 3][0] = *(const float4*)(Arow + (s + 2) * 32);
            abuf[(s + 2) % 3][1] = *(const float4*)(Arow + (s + 2) * 32 + 4);
        }
        if (s + 1 < NSTEP) {
#pragma unroll
            for (int nf = 0; nf < 8; nf++)
                pb[nf] = *(const short8*)(Bbase + (size_t)nf * 16 * K + (s + 1) * 32);
        }
        float4 a0 = abuf[s % 3][0];
        float4 a1 = abuf[s % 3][1];
        float av[8] = {a0.x, a0.y, a0.z, a0.w, a1.x, a1.y, a1.z, a1.w};
        if (XFORM) {
            const int kk = s * 32 + g * 8;
#pragma unroll
            for (int j = 0; j < 8; j++) {
                float v = fmaf(av[j], bnp[kk + j], bnp[128 + kk + j]);
                av[j] = v >= 0.f ? v : alpha * v;
            }
        }
        short8 af;
#pragma unroll
        for (int j = 0; j < 8; j++) af[j] = bf16_rne(av[j]);
#pragma unroll
        for (int nf = 0; nf < 8; nf++)
            acc[nf] = __builtin_amdgcn_mfma_f32_16x16x32_bf16(af, cb[nf], acc[nf], 0, 0, 0);
        if (s + 1 < NSTEP) {
#pragma unroll
            for (int nf = 0; nf < 8; nf++) cb[nf] = pb[nf];
        }
    }
#pragma unroll
    for (int r = 0; r < 4; r++) {
        const int row = row0 + g * 4 + r;
        if (row < M) {
            const float dv = dinv[row];
#pragma unroll
            for (int nf = 0; nf < 8; nf++) {
                out[(size_t)row * OUT_DIM + nf * 16 + r16] = acc[nf][r] * dv;
            }
        }
    }
}

// ---------------- Aggregation (1 node per wave, float2 per lane) ----------------

__global__ __launch_bounds__(256) void agg_kernel(
        const float* __restrict__ h, const int* __restrict__ rowp,
        const int* __restrict__ col, const float* __restrict__ dinv,
        const float* __restrict__ bias, float* __restrict__ out, int n) {
    const int wave = threadIdx.x >> 6;
    const int lane = threadIdx.x & 63;
    const int node = (blockIdx.x << 2) + wave;
    if (node >= n) return;
    const int f = lane << 1;
    int e = rowp[node];
    const int end = rowp[node + 1];
    float a0 = 0.f, a1 = 0.f;
    for (; e + 4 <= end; e += 4) {
        int c0 = col[e], c1 = col[e + 1], c2 = col[e + 2], c3 = col[e + 3];
        float2 h0 = *(const float2*)(h + (size_t)c0 * OUT_DIM + f);
        float2 h1 = *(const float2*)(h + (size_t)c1 * OUT_DIM + f);
        float2 h2 = *(const float2*)(h + (size_t)c2 * OUT_DIM + f);
        float2 h3 = *(const float2*)(h + (size_t)c3 * OUT_DIM + f);
        a0 += (h0.x + h1.x) + (h2.x + h3.x);
        a1 += (h0.y + h1.y) + (h2.y + h3.y);
    }
    for (; e < end; ++e) {
        int s = col[e];
        float2 hv = *(const float2*)(h + (size_t)s * OUT_DIM + f);
        a0 += hv.x; a1 += hv.y;
    }
    float dn = dinv[node];
    a0 = fmaf(a0, dn, bias[f]);
    a1 = fmaf(a1, dn, bias[f + 1]);
    *(float2*)(out + (size_t)node * OUT_DIM + f) = make_float2(a0, a1);
}

// ---------------- BN stats over agg output ----------------

__global__ __launch_bounds__(256) void bn_stats(const float* __restrict__ out,
                                                float* __restrict__ stats, int n) {
    const int wave = threadIdx.x >> 6;
    const int lane = threadIdx.x & 63;
    const int f = lane << 1;
    float s0 = 0.f, s1 = 0.f, q0 = 0.f, q1 = 0.f;
    for (int node = (blockIdx.x << 2) + wave; node < n; node += (gridDim.x << 2)) {
        float2 v = *(const float2*)(out + (size_t)node * OUT_DIM + f);
        s0 += v.x; s1 += v.y;
        q0 = fmaf(v.x, v.x, q0); q1 = fmaf(v.y, v.y, q1);
    }
    __shared__ float red[4][256];
    red[wave][f] = s0;        red[wave][f + 1] = s1;
    red[wave][128 + f] = q0;  red[wave][128 + f + 1] = q1;
    __syncthreads();
    int t = threadIdx.x;
    float v = red[0][t] + red[1][t] + red[2][t] + red[3][t];
    atomicAdd(&stats[t], v);
}

__global__ void bn_finalize(const float* __restrict__ stats, const float* __restrict__ g,
                            const float* __restrict__ be, float* __restrict__ bnp, float inv_n) {
    int f = threadIdx.x;  // 128
    float mean = stats[f] * inv_n;
    float var = stats[128 + f] * inv_n - mean * mean;
    var = fmaxf(var, 0.f);
    float sc = g[f] * rsqrtf(var + BN_EPS);
    bnp[f] = sc;
    bnp[128 + f] = be[f] - mean * sc;
}

// ---------------- launch ----------------

extern "C" void kernel_launch(void* const* d_in, const int* in_sizes, int n_in,
                              void* d_out, int out_size, void* d_ws, size_t ws_size,
                              hipStream_t stream) {
    const float* x   = (const float*)d_in[0];
    const int*   ei  = (const int*)d_in[1];
    const float* W1  = (const float*)d_in[2];
    const float* b1  = (const float*)d_in[3];
    const float* W2  = (const float*)d_in[4];
    const float* b2  = (const float*)d_in[5];
    const float* W3  = (const float*)d_in[6];
    const float* b3  = (const float*)d_in[7];
    const float* g1  = (const float*)d_in[8];
    const float* be1 = (const float*)d_in[9];
    const float* g2  = (const float*)d_in[10];
    const float* be2 = (const float*)d_in[11];
    const float* a1  = (const float*)d_in[12];
    const float* a2  = (const float*)d_in[13];

    const int n = N_NODES;
    const int E = in_sizes[1] / 2;
    float* out = (float*)d_out;

    char* ws = (char*)d_ws;
    size_t off = 0;
    auto alloc = [&](size_t bytes) { void* p = ws + off; off += (bytes + 255) & ~(size_t)255; return p; };
    float* bufA  = (float*)alloc((size_t)n * OUT_DIM * sizeof(float));
    int*   cnt   = (int*)alloc((size_t)n * sizeof(int));
    int*   rowp  = (int*)alloc((size_t)(n + 1) * sizeof(int));
    float* dinv  = (float*)alloc((size_t)n * sizeof(float));
    int*   col   = (int*)alloc((size_t)(E + n) * sizeof(int));
    float* stats = (float*)alloc(512 * sizeof(float));
    float* bnp1  = (float*)alloc(256 * sizeof(float));
    float* bnp2  = (float*)alloc(256 * sizeof(float));
    short* Wt1   = (short*)alloc((size_t)IN_DIM * OUT_DIM * sizeof(short));
    short* Wt2   = (short*)alloc((size_t)OUT_DIM * OUT_DIM * sizeof(short));
    short* Wt3   = (short*)alloc((size_t)OUT_DIM * OUT_DIM * sizeof(short));

    hipLaunchKernelGGL(init_kernel, dim3((n + 255) / 256), dim3(256), 0, stream, cnt, stats, n);
    hipLaunchKernelGGL(deg_kernel, dim3((E + 255) / 256), dim3(256), 0, stream, ei, cnt, E);
    hipLaunchKernelGGL(scan_kernel, dim3(1), dim3(1024), 0, stream, cnt, rowp, n);
    hipLaunchKernelGGL(selfloop_kernel, dim3((n + 255) / 256), dim3(256), 0, stream, cnt, rowp, dinv, col, n);
    hipLaunchKernelGGL(fill_kernel, dim3((E + 255) / 256), dim3(256), 0, stream, ei, cnt, col, E);
    hipLaunchKernelGGL(wconv_kernel, dim3(IN_DIM / 64), dim3(256), 0, stream, W1, Wt1, IN_DIM);
    hipLaunchKernelGGL(wconv_kernel, dim3(OUT_DIM / 64), dim3(256), 0, stream, W2, Wt2, OUT_DIM);
    hipLaunchKernelGGL(wconv_kernel, dim3(OUT_DIM / 64), dim3(256), 0, stream, W3, Wt3, OUT_DIM);

    const int gblocks = (n + 31) / 32;        // 32 rows per block (2 waves x 16)
    const int ablocks = (n + 3) / 4;          // one node per wave
    // layer 1
    hipLaunchKernelGGL((mfma_gemm<IN_DIM, false>), dim3(gblocks), dim3(128), 0, stream,
                       x, Wt1, bufA, n, nullptr, nullptr, dinv);
    hipLaunchKernelGGL(agg_kernel, dim3(ablocks), dim3(256), 0, stream,
                       bufA, rowp, col, dinv, b1, out, n);
    hipLaunchKernelGGL(bn_stats, dim3(256), dim3(256), 0, stream, out, stats, n);
    hipLaunchKernelGGL(bn_finalize, dim3(1), dim3(128), 0, stream, stats, g1, be1, bnp1, 1.0f / n);
    // layer 2
    hipLaunchKernelGGL((mfma_gemm<OUT_DIM, true>), dim3(gblocks), dim3(128), 0, stream,
                       out, Wt2, bufA, n, bnp1, a1, dinv);
    hipLaunchKernelGGL(agg_kernel, dim3(ablocks), dim3(256), 0, stream,
                       bufA, rowp, col, dinv, b2, out, n);
    hipLaunchKernelGGL(bn_stats, dim3(256), dim3(256), 0, stream, out, stats + 256, n);
    hipLaunchKernelGGL(bn_finalize, dim3(1), dim3(128), 0, stream, stats + 256, g2, be2, bnp2, 1.0f / n);
    // layer 3
    hipLaunchKernelGGL((mfma_gemm<OUT_DIM, true>), dim3(gblocks), dim3(128), 0, stream,
                       out, Wt3, bufA, n, bnp2, a2, dinv);
    hipLaunchKernelGGL(agg_kernel, dim3(ablocks), dim3(256), 0, stream,
                       bufA, rowp, col, dinv, b3, out, n);
}

// Round 5
// 456.425 us; speedup vs baseline: 2.3047x; 1.0971x over previous
//
#include <hip/hip_runtime.h>

#define N_NODES 50000
#define IN_DIM  512
#define OUT_DIM 128
#define BN_EPS  1e-5f

typedef __attribute__((ext_vector_type(8))) short short8;
typedef __attribute__((ext_vector_type(4))) float f32x4;

__device__ __forceinline__ unsigned short bf16_rne(float x) {
    unsigned u = __float_as_uint(x);
    unsigned r = (u + 0x7FFFu + ((u >> 16) & 1u)) >> 16;
    return (unsigned short)r;
}
__device__ __forceinline__ float bf16_to_f(unsigned short s) {
    return __uint_as_float(((unsigned)s) << 16);
}

// ---------------- CSR build ----------------

__global__ void init_kernel(int* __restrict__ cnt, float* __restrict__ stats, int n) {
    int i = blockIdx.x * blockDim.x + threadIdx.x;
    if (i < n) cnt[i] = 1;            // self-loop contributes 1 to every in-degree
    if (i < 512) stats[i] = 0.f;      // zero BN stat accumulators (both layers)
}

__device__ __forceinline__ int edge_is64(const int* ei) {
    return (ei[1] | ei[3] | ei[5] | ei[7]) == 0;
}

__global__ void deg_kernel(const int* __restrict__ ei, int* __restrict__ cnt, int E) {
    int e = blockIdx.x * blockDim.x + threadIdx.x;
    if (e >= E) return;
    int is64 = edge_is64(ei);
    int dst = is64 ? ei[2 * E + 2 * e] : ei[E + e];
    atomicAdd(&cnt[dst], 1);
}

__global__ __launch_bounds__(1024) void scan_kernel(const int* __restrict__ cnt,
                                                    int* __restrict__ rowp, int n) {
    __shared__ int wsum[16];
    __shared__ int chunk_base;
    const int tid = threadIdx.x;
    const int lane = tid & 63;
    const int wv = tid >> 6;
    if (tid == 0) chunk_base = 0;
    __syncthreads();
    for (int base = 0; base < n + 1023; base += 1024) {
        int i = base + tid;
        int orig = (i < n) ? cnt[i] : 0;
        int v = orig;
#pragma unroll
        for (int d = 1; d < 64; d <<= 1) {
            int t = __shfl_up(v, d);
            if (lane >= d) v += t;
        }
        if (lane == 63) wsum[wv] = v;
        __syncthreads();
        int woff = 0;
        for (int w = 0; w < wv; ++w) woff += wsum[w];
        int cb = chunk_base;
        if (i < n) rowp[i] = cb + woff + v - orig;
        int newbase = cb + woff + v;
        __syncthreads();
        if (tid == 1023) chunk_base = newbase;
        __syncthreads();
    }
    if (tid == 0) rowp[n] = chunk_base;
}

__global__ void selfloop_kernel(int* __restrict__ cnt, const int* __restrict__ rowp,
                                float* __restrict__ dinv, int* __restrict__ col, int n) {
    int i = blockIdx.x * blockDim.x + threadIdx.x;
    if (i >= n) return;
    int deg = cnt[i];
    dinv[i] = rsqrtf(fmaxf((float)deg, 1.f));
    int rp = rowp[i];
    col[rp] = i;          // self loop first
    cnt[i] = rp + 1;      // cursor for edge fill
}

__global__ void fill_kernel(const int* __restrict__ ei, int* __restrict__ cnt,
                            int* __restrict__ col, int E) {
    int e = blockIdx.x * blockDim.x + threadIdx.x;
    if (e >= E) return;
    int is64 = edge_is64(ei);
    int src, dst;
    if (is64) { src = ei[2 * e];     dst = ei[2 * E + 2 * e]; }
    else      { src = ei[e];         dst = ei[E + e]; }
    int pos = atomicAdd(&cnt[dst], 1);
    col[pos] = src;
}

// ---------------- W convert+transpose: [K][128] fp32 -> [128][K] bf16 ----------------

__global__ __launch_bounds__(256) void wconv_kernel(const float* __restrict__ W,
                                                    short* __restrict__ Wt, int K) {
    __shared__ short tile[64][130];
    const int k0 = blockIdx.x * 64;
    for (int i = threadIdx.x; i < 64 * 128; i += 256) {
        int k = i >> 7, c = i & 127;
        tile[k][c] = (short)bf16_rne(W[(size_t)(k0 + k) * 128 + c]);
    }
    __syncthreads();
    for (int i = threadIdx.x; i < 64 * 128; i += 256) {
        int c = i >> 6, k = i & 63;
        Wt[(size_t)c * K + k0 + k] = tile[k][c];
    }
}

// ---------------- MFMA GEMM, LDS-staged (m97-style), bf16 out ----------------
// BM=64 (4 waves x 16 rows x 128 cols), BK=64, single-buffered LDS with
// stage->barrier->write->barrier->compute per k-step. XOR swizzle on 16B
// units: phys = q ^ (row&7), applied identically on write and read.
// k-map self-consistent: k = (lane>>4)*8 + j for A and B. C/D: col=lane&15,
// row=(lane>>4)*4+reg. Epilogue: *dinv[row], store bf16.

template <typename TA, int K, bool XFORM>
__global__ __launch_bounds__(256, 2) void mfma_gemm(
        const TA* __restrict__ A, const short* __restrict__ Wt,
        unsigned short* __restrict__ out, int M,
        const float* __restrict__ bnp, const float* __restrict__ alpha_p,
        const float* __restrict__ dinv) {
    constexpr int BK = 64;
    constexpr int NSTEP = K / BK;
    constexpr int UPRA = (BK * (int)sizeof(TA)) / 16;   // 16B units per A row (16 fp32 / 8 bf16)
    constexpr int AINST = 64 * UPRA / 256;              // 4 or 2
    __shared__ TA    ldsA[64 * BK];
    __shared__ short ldsB[128 * BK];
    float4* ldsA4 = (float4*)ldsA;
    float4* ldsB4 = (float4*)ldsB;

    const int tid  = threadIdx.x;
    const int lane = tid & 63;
    const int wv   = tid >> 6;
    const int r16  = lane & 15;
    const int g    = lane >> 4;
    const int row0 = blockIdx.x * 64;
    const int arow_t = wv * 16 + r16;         // this lane's A row within the tile

    const float alpha = XFORM ? alpha_p[0] : 0.f;

    f32x4 acc[8];
#pragma unroll
    for (int nf = 0; nf < 8; nf++) acc[nf] = (f32x4)(0.f);

    for (int s = 0; s < NSTEP; ++s) {
        const int k0 = s * BK;
        float4 ra[AINST], rb[4];
#pragma unroll
        for (int i = 0; i < AINST; ++i) {
            int d = i * 256 + tid;
            int row = d / UPRA, q = d % UPRA;
            int grow = row0 + row; if (grow >= M) grow = M - 1;
            ra[i] = *(const float4*)((const char*)(A + (size_t)grow * K + k0) + q * 16);
        }
#pragma unroll
        for (int i = 0; i < 4; ++i) {
            int d = i * 256 + tid;
            int colb = d >> 3, q = d & 7;
            rb[i] = *(const float4*)(Wt + (size_t)colb * K + k0 + q * 8);
        }
        __syncthreads();              // previous step's LDS reads complete
#pragma unroll
        for (int i = 0; i < AINST; ++i) {
            int d = i * 256 + tid;
            int row = d / UPRA, q = d % UPRA;
            ldsA4[row * UPRA + (q ^ (row & 7))] = ra[i];
        }
#pragma unroll
        for (int i = 0; i < 4; ++i) {
            int d = i * 256 + tid;
            int colb = d >> 3, q = d & 7;
            ldsB4[colb * 8 + (q ^ (colb & 7))] = rb[i];
        }
        __syncthreads();              // tile visible
#pragma unroll
        for (int ksub = 0; ksub < 2; ++ksub) {
            short8 af;
            if constexpr (sizeof(TA) == 4) {
                const int q0 = ksub * 8 + g * 2;
                float4 alo = ldsA4[arow_t * UPRA + (q0 ^ (r16 & 7))];
                float4 ahi = ldsA4[arow_t * UPRA + ((q0 + 1) ^ (r16 & 7))];
                float av[8] = {alo.x, alo.y, alo.z, alo.w, ahi.x, ahi.y, ahi.z, ahi.w};
#pragma unroll
                for (int j = 0; j < 8; j++) af[j] = (short)bf16_rne(av[j]);
            } else {
                short8 raw = ((const short8*)ldsA)[arow_t * 8 + ((ksub * 4 + g) ^ (r16 & 7))];
                if constexpr (XFORM) {
                    const int kk = k0 + ksub * 32 + g * 8;
                    float4 sc0 = *(const float4*)(bnp + kk);
                    float4 sc1 = *(const float4*)(bnp + kk + 4);
                    float4 sh0 = *(const float4*)(bnp + 128 + kk);
                    float4 sh1 = *(const float4*)(bnp + 128 + kk + 4);
                    float scv[8] = {sc0.x, sc0.y, sc0.z, sc0.w, sc1.x, sc1.y, sc1.z, sc1.w};
                    float shv[8] = {sh0.x, sh0.y, sh0.z, sh0.w, sh1.x, sh1.y, sh1.z, sh1.w};
#pragma unroll
                    for (int j = 0; j < 8; j++) {
                        float v = fmaf(bf16_to_f((unsigned short)raw[j]), scv[j], shv[j]);
                        v = v >= 0.f ? v : alpha * v;
                        af[j] = (short)bf16_rne(v);
                    }
                } else {
                    af = raw;
                }
            }
#pragma unroll
            for (int nf = 0; nf < 8; nf++) {
                const int colb = nf * 16 + r16;
                short8 bf = ((const short8*)ldsB)[colb * 8 + ((ksub * 4 + g) ^ (r16 & 7))];
                acc[nf] = __builtin_amdgcn_mfma_f32_16x16x32_bf16(af, bf, acc[nf], 0, 0, 0);
            }
        }
    }
#pragma unroll
    for (int r = 0; r < 4; ++r) {
        const int row = row0 + wv * 16 + g * 4 + r;
        if (row < M) {
            const float dv = dinv[row];
#pragma unroll
            for (int nf = 0; nf < 8; nf++)
                out[(size_t)row * OUT_DIM + nf * 16 + r16] = bf16_rne(acc[nf][r] * dv);
        }
    }
}

// ---------------- Aggregation (1 node per wave, 2 bf16 feats per lane) ----------------

template <int OUT32>
__global__ __launch_bounds__(256) void agg_kernel(
        const unsigned short* __restrict__ h, const int* __restrict__ rowp,
        const int* __restrict__ col, const float* __restrict__ dinv,
        const float* __restrict__ bias, void* __restrict__ outv, int n) {
    const int wave = threadIdx.x >> 6;
    const int lane = threadIdx.x & 63;
    const int node = (blockIdx.x << 2) + wave;
    if (node >= n) return;
    const int f = lane << 1;
    int e = rowp[node];
    const int end = rowp[node + 1];
    float a0 = 0.f, a1 = 0.f;
    for (; e + 4 <= end; e += 4) {
        int c0 = col[e], c1 = col[e + 1], c2 = col[e + 2], c3 = col[e + 3];
        unsigned v0 = *(const unsigned*)(h + (size_t)c0 * OUT_DIM + f);
        unsigned v1 = *(const unsigned*)(h + (size_t)c1 * OUT_DIM + f);
        unsigned v2 = *(const unsigned*)(h + (size_t)c2 * OUT_DIM + f);
        unsigned v3 = *(const unsigned*)(h + (size_t)c3 * OUT_DIM + f);
        a0 += __uint_as_float(v0 << 16) + __uint_as_float(v1 << 16)
            + __uint_as_float(v2 << 16) + __uint_as_float(v3 << 16);
        a1 += __uint_as_float(v0 & 0xFFFF0000u) + __uint_as_float(v1 & 0xFFFF0000u)
            + __uint_as_float(v2 & 0xFFFF0000u) + __uint_as_float(v3 & 0xFFFF0000u);
    }
    for (; e < end; ++e) {
        unsigned v = *(const unsigned*)(h + (size_t)col[e] * OUT_DIM + f);
        a0 += __uint_as_float(v << 16);
        a1 += __uint_as_float(v & 0xFFFF0000u);
    }
    float dn = dinv[node];
    a0 = fmaf(a0, dn, bias[f]);
    a1 = fmaf(a1, dn, bias[f + 1]);
    if (OUT32) {
        ((float2*)outv)[(size_t)node * 64 + lane] = make_float2(a0, a1);
    } else {
        unsigned p = ((unsigned)bf16_rne(a1) << 16) | (unsigned)bf16_rne(a0);
        ((unsigned*)outv)[(size_t)node * 64 + lane] = p;
    }
}

// ---------------- BN stats over bf16 buffer ----------------

__global__ __launch_bounds__(256) void bn_stats(const unsigned short* __restrict__ h,
                                                float* __restrict__ stats, int n) {
    const int wave = threadIdx.x >> 6;
    const int lane = threadIdx.x & 63;
    const int f = lane << 1;
    float s0 = 0.f, s1 = 0.f, q0 = 0.f, q1 = 0.f;
    for (int node = (blockIdx.x << 2) + wave; node < n; node += (gridDim.x << 2)) {
        unsigned v = *(const unsigned*)(h + (size_t)node * OUT_DIM + f);
        float x0 = __uint_as_float(v << 16);
        float x1 = __uint_as_float(v & 0xFFFF0000u);
        s0 += x0; s1 += x1;
        q0 = fmaf(x0, x0, q0); q1 = fmaf(x1, x1, q1);
    }
    __shared__ float red[4][256];
    red[wave][f] = s0;        red[wave][f + 1] = s1;
    red[wave][128 + f] = q0;  red[wave][128 + f + 1] = q1;
    __syncthreads();
    int t = threadIdx.x;
    float v = red[0][t] + red[1][t] + red[2][t] + red[3][t];
    atomicAdd(&stats[t], v);
}

__global__ void bn_finalize(const float* __restrict__ stats, const float* __restrict__ g,
                            const float* __restrict__ be, float* __restrict__ bnp, float inv_n) {
    int f = threadIdx.x;  // 128
    float mean = stats[f] * inv_n;
    float var = stats[128 + f] * inv_n - mean * mean;
    var = fmaxf(var, 0.f);
    float sc = g[f] * rsqrtf(var + BN_EPS);
    bnp[f] = sc;
    bnp[128 + f] = be[f] - mean * sc;
}

// ---------------- launch ----------------

extern "C" void kernel_launch(void* const* d_in, const int* in_sizes, int n_in,
                              void* d_out, int out_size, void* d_ws, size_t ws_size,
                              hipStream_t stream) {
    const float* x   = (const float*)d_in[0];
    const int*   ei  = (const int*)d_in[1];
    const float* W1  = (const float*)d_in[2];
    const float* b1  = (const float*)d_in[3];
    const float* W2  = (const float*)d_in[4];
    const float* b2  = (const float*)d_in[5];
    const float* W3  = (const float*)d_in[6];
    const float* b3  = (const float*)d_in[7];
    const float* g1  = (const float*)d_in[8];
    const float* be1 = (const float*)d_in[9];
    const float* g2  = (const float*)d_in[10];
    const float* be2 = (const float*)d_in[11];
    const float* a1  = (const float*)d_in[12];
    const float* a2  = (const float*)d_in[13];

    const int n = N_NODES;
    const int E = in_sizes[1] / 2;
    float* out = (float*)d_out;

    char* ws = (char*)d_ws;
    size_t off = 0;
    auto alloc = [&](size_t bytes) { void* p = ws + off; off += (bytes + 255) & ~(size_t)255; return p; };
    unsigned short* bufA = (unsigned short*)alloc((size_t)n * OUT_DIM * sizeof(short)); // GEMM out (bf16)
    unsigned short* hb   = (unsigned short*)alloc((size_t)n * OUT_DIM * sizeof(short)); // agg out (bf16)
    int*   cnt   = (int*)alloc((size_t)n * sizeof(int));
    int*   rowp  = (int*)alloc((size_t)(n + 1) * sizeof(int));
    float* dinv  = (float*)alloc((size_t)n * sizeof(float));
    int*   col   = (int*)alloc((size_t)(E + n) * sizeof(int));
    float* stats = (float*)alloc(512 * sizeof(float));
    float* bnp1  = (float*)alloc(256 * sizeof(float));
    float* bnp2  = (float*)alloc(256 * sizeof(float));
    short* Wt1   = (short*)alloc((size_t)IN_DIM * OUT_DIM * sizeof(short));
    short* Wt2   = (short*)alloc((size_t)OUT_DIM * OUT_DIM * sizeof(short));
    short* Wt3   = (short*)alloc((size_t)OUT_DIM * OUT_DIM * sizeof(short));

    hipLaunchKernelGGL(init_kernel, dim3((n + 255) / 256), dim3(256), 0, stream, cnt, stats, n);
    hipLaunchKernelGGL(deg_kernel, dim3((E + 255) / 256), dim3(256), 0, stream, ei, cnt, E);
    hipLaunchKernelGGL(scan_kernel, dim3(1), dim3(1024), 0, stream, cnt, rowp, n);
    hipLaunchKernelGGL(selfloop_kernel, dim3((n + 255) / 256), dim3(256), 0, stream, cnt, rowp, dinv, col, n);
    hipLaunchKernelGGL(fill_kernel, dim3((E + 255) / 256), dim3(256), 0, stream, ei, cnt, col, E);
    hipLaunchKernelGGL(wconv_kernel, dim3(IN_DIM / 64), dim3(256), 0, stream, W1, Wt1, IN_DIM);
    hipLaunchKernelGGL(wconv_kernel, dim3(OUT_DIM / 64), dim3(256), 0, stream, W2, Wt2, OUT_DIM);
    hipLaunchKernelGGL(wconv_kernel, dim3(OUT_DIM / 64), dim3(256), 0, stream, W3, Wt3, OUT_DIM);

    const int gblocks = (n + 63) / 64;        // 64 rows per block
    const int ablocks = (n + 3) / 4;          // one node per wave
    // layer 1
    hipLaunchKernelGGL((mfma_gemm<float, IN_DIM, false>), dim3(gblocks), dim3(256), 0, stream,
                       x, Wt1, bufA, n, nullptr, nullptr, dinv);
    hipLaunchKernelGGL((agg_kernel<0>), dim3(ablocks), dim3(256), 0, stream,
                       bufA, rowp, col, dinv, b1, hb, n);
    hipLaunchKernelGGL(bn_stats, dim3(256), dim3(256), 0, stream, hb, stats, n);
    hipLaunchKernelGGL(bn_finalize, dim3(1), dim3(128), 0, stream, stats, g1, be1, bnp1, 1.0f / n);
    // layer 2
    hipLaunchKernelGGL((mfma_gemm<short, OUT_DIM, true>), dim3(gblocks), dim3(256), 0, stream,
                       (const short*)hb, Wt2, bufA, n, bnp1, a1, dinv);
    hipLaunchKernelGGL((agg_kernel<0>), dim3(ablocks), dim3(256), 0, stream,
                       bufA, rowp, col, dinv, b2, hb, n);
    hipLaunchKernelGGL(bn_stats, dim3(256), dim3(256), 0, stream, hb, stats + 256, n);
    hipLaunchKernelGGL(bn_finalize, dim3(1), dim3(128), 0, stream, stats + 256, g2, be2, bnp2, 1.0f / n);
    // layer 3
    hipLaunchKernelGGL((mfma_gemm<short, OUT_DIM, true>), dim3(gblocks), dim3(256), 0, stream,
                       (const short*)hb, Wt3, bufA, n, bnp2, a2, dinv);
    hipLaunchKernelGGL((agg_kernel<1>), dim3(ablocks), dim3(256), 0, stream,
                       bufA, rowp, col, dinv, b3, out, n);
}

// Round 6
// 383.843 us; speedup vs baseline: 2.7404x; 1.1891x over previous
//
#include <hip/hip_runtime.h>

#define N_NODES 50000
#define IN_DIM  512
#define OUT_DIM 128
#define BN_EPS  1e-5f

typedef __attribute__((ext_vector_type(8))) short short8;
typedef __attribute__((ext_vector_type(4))) float f32x4;

__device__ __forceinline__ unsigned short bf16_rne(float x) {
    unsigned u = __float_as_uint(x);
    unsigned r = (u + 0x7FFFu + ((u >> 16) & 1u)) >> 16;
    return (unsigned short)r;
}
__device__ __forceinline__ float bf16_to_f(unsigned short s) {
    return __uint_as_float(((unsigned)s) << 16);
}

// global -> LDS direct staging, 16B per lane. lds dest must be wave-uniform;
// HW adds lane*16.
__device__ __forceinline__ void gload16(const void* g, void* l) {
    __builtin_amdgcn_global_load_lds(
        (const __attribute__((address_space(1))) void*)g,
        (__attribute__((address_space(3))) void*)l, 16, 0, 0);
}

// ---------------- CSR build ----------------

__global__ void init_kernel(int* __restrict__ cnt, float* __restrict__ stats, int n) {
    int i = blockIdx.x * blockDim.x + threadIdx.x;
    if (i < n) cnt[i] = 1;            // self-loop contributes 1 to every in-degree
    if (i < 512) stats[i] = 0.f;      // zero BN stat accumulators (both layers)
}

__device__ __forceinline__ int edge_is64(const int* ei) {
    return (ei[1] | ei[3] | ei[5] | ei[7]) == 0;
}

__global__ void deg_kernel(const int* __restrict__ ei, int* __restrict__ cnt, int E) {
    int e = blockIdx.x * blockDim.x + threadIdx.x;
    if (e >= E) return;
    int is64 = edge_is64(ei);
    int dst = is64 ? ei[2 * E + 2 * e] : ei[E + e];
    atomicAdd(&cnt[dst], 1);
}

__global__ __launch_bounds__(1024) void scan_kernel(const int* __restrict__ cnt,
                                                    int* __restrict__ rowp, int n) {
    __shared__ int wsum[16];
    __shared__ int chunk_base;
    const int tid = threadIdx.x;
    const int lane = tid & 63;
    const int wv = tid >> 6;
    if (tid == 0) chunk_base = 0;
    __syncthreads();
    for (int base = 0; base < n + 1023; base += 1024) {
        int i = base + tid;
        int orig = (i < n) ? cnt[i] : 0;
        int v = orig;
#pragma unroll
        for (int d = 1; d < 64; d <<= 1) {
            int t = __shfl_up(v, d);
            if (lane >= d) v += t;
        }
        if (lane == 63) wsum[wv] = v;
        __syncthreads();
        int woff = 0;
        for (int w = 0; w < wv; ++w) woff += wsum[w];
        int cb = chunk_base;
        if (i < n) rowp[i] = cb + woff + v - orig;
        int newbase = cb + woff + v;
        __syncthreads();
        if (tid == 1023) chunk_base = newbase;
        __syncthreads();
    }
    if (tid == 0) rowp[n] = chunk_base;
}

__global__ void selfloop_kernel(int* __restrict__ cnt, const int* __restrict__ rowp,
                                float* __restrict__ dinv, int* __restrict__ col, int n) {
    int i = blockIdx.x * blockDim.x + threadIdx.x;
    if (i >= n) return;
    int deg = cnt[i];
    dinv[i] = rsqrtf(fmaxf((float)deg, 1.f));
    int rp = rowp[i];
    col[rp] = i;          // self loop first
    cnt[i] = rp + 1;      // cursor for edge fill
}

__global__ void fill_kernel(const int* __restrict__ ei, int* __restrict__ cnt,
                            int* __restrict__ col, int E) {
    int e = blockIdx.x * blockDim.x + threadIdx.x;
    if (e >= E) return;
    int is64 = edge_is64(ei);
    int src, dst;
    if (is64) { src = ei[2 * e];     dst = ei[2 * E + 2 * e]; }
    else      { src = ei[e];         dst = ei[E + e]; }
    int pos = atomicAdd(&cnt[dst], 1);
    col[pos] = src;
}

// ---------------- W convert+transpose: [K][128] fp32 -> [128][K] bf16 ----------------

__global__ __launch_bounds__(256) void wconv_kernel(const float* __restrict__ W,
                                                    short* __restrict__ Wt, int K) {
    __shared__ short tile[64][130];
    const int k0 = blockIdx.x * 64;
    for (int i = threadIdx.x; i < 64 * 128; i += 256) {
        int k = i >> 7, c = i & 127;
        tile[k][c] = (short)bf16_rne(W[(size_t)(k0 + k) * 128 + c]);
    }
    __syncthreads();
    for (int i = threadIdx.x; i < 64 * 128; i += 256) {
        int c = i >> 6, k = i & 63;
        Wt[(size_t)c * K + k0 + k] = tile[k][c];
    }
}

// ---------------- MFMA GEMM, global_load_lds staged (m97 structure) ----------------
// BM=64 (4 waves x 16 rows x 128 cols), BK=64. Staging: HBM->LDS direct, LDS
// linear, XOR swizzle applied to the GLOBAL source unit (involution) and to
// the ds_read unit. k-map self-consistent: k = (lane>>4)*8 + j for A and B.
// C/D: col=lane&15, row=(lane>>4)*4+reg. Epilogue: *dinv[row], LDS transpose,
// coalesced dwordx4 bf16 stores.

template <typename TA, int K, bool XFORM>
__global__ __launch_bounds__(256) void mfma_gemm(
        const TA* __restrict__ A, const short* __restrict__ Wt,
        unsigned short* __restrict__ out, int M,
        const float* __restrict__ bnp, const float* __restrict__ alpha_p,
        const float* __restrict__ dinv) {
    constexpr int BK = 64;
    constexpr int NSTEP = K / BK;
    constexpr int UPRA = (BK * (int)sizeof(TA)) / 16;   // 16B units per A row
    constexpr int AINST = 64 * UPRA / 256;              // 4 (fp32) or 2 (bf16)
    __shared__ TA    ldsA[64 * BK];
    __shared__ short ldsB[128 * BK];

    const int tid  = threadIdx.x;
    const int lane = tid & 63;
    const int wv   = tid >> 6;
    const int r16  = lane & 15;
    const int g    = lane >> 4;
    const int row0 = blockIdx.x * 64;
    const int arow_t = wv * 16 + r16;         // this lane's A row within the tile

    const float alpha = XFORM ? alpha_p[0] : 0.f;

    f32x4 acc[8];
#pragma unroll
    for (int nf = 0; nf < 8; nf++) acc[nf] = (f32x4)(0.f);

    for (int s = 0; s < NSTEP; ++s) {
        const int k0 = s * BK;
        if (s) __syncthreads();               // prev step's LDS reads done
        // ---- stage A: linear LDS dest, inverse-swizzled global source ----
#pragma unroll
        for (int i = 0; i < AINST; ++i) {
            const int d   = i * 256 + tid;
            const int row = d / UPRA, p = d % UPRA;
            int grow = row0 + row; if (grow >= M) grow = M - 1;
            const char* src = (const char*)(A + (size_t)grow * K + k0) + ((p ^ (row & 7)) * 16);
            gload16(src, (char*)ldsA + (size_t)(i * 256 + wv * 64) * 16);
        }
        // ---- stage B ----
#pragma unroll
        for (int i = 0; i < 4; ++i) {
            const int d    = i * 256 + tid;
            const int colb = d >> 3, p = d & 7;
            const short* src = Wt + (size_t)colb * K + k0 + (p ^ (colb & 7)) * 8;
            gload16(src, (char*)ldsB + (size_t)(i * 256 + wv * 64) * 16);
        }
        __syncthreads();                      // drains vmcnt; tile visible
#pragma unroll
        for (int ksub = 0; ksub < 2; ++ksub) {
            short8 af;
            if constexpr (sizeof(TA) == 4) {
                const int q0 = ksub * 8 + g * 2;
                const float4* A4 = (const float4*)ldsA;
                float4 alo = A4[arow_t * UPRA + (q0 ^ (r16 & 7))];
                float4 ahi = A4[arow_t * UPRA + ((q0 + 1) ^ (r16 & 7))];
                float av[8] = {alo.x, alo.y, alo.z, alo.w, ahi.x, ahi.y, ahi.z, ahi.w};
#pragma unroll
                for (int j = 0; j < 8; j++) af[j] = (short)bf16_rne(av[j]);
            } else {
                short8 raw = ((const short8*)ldsA)[arow_t * 8 + ((ksub * 4 + g) ^ (r16 & 7))];
                if constexpr (XFORM) {
                    const int kk = k0 + ksub * 32 + g * 8;
#pragma unroll
                    for (int j = 0; j < 8; j++) {
                        float v = fmaf(bf16_to_f((unsigned short)raw[j]), bnp[kk + j], bnp[128 + kk + j]);
                        v = v >= 0.f ? v : alpha * v;
                        af[j] = (short)bf16_rne(v);
                    }
                } else {
                    af = raw;
                }
            }
#pragma unroll
            for (int nf = 0; nf < 8; nf++) {
                const int colb = nf * 16 + r16;
                short8 bf = ((const short8*)ldsB)[colb * 8 + ((ksub * 4 + g) ^ (r16 & 7))];
                acc[nf] = __builtin_amdgcn_mfma_f32_16x16x32_bf16(af, bf, acc[nf], 0, 0, 0);
            }
        }
    }

    // ---- epilogue: acc -> LDS (bf16, reuse ldsB) -> coalesced stores ----
    __syncthreads();                          // all K-loop LDS reads done
    unsigned short* ot = (unsigned short*)ldsB;   // 64 x 128 bf16 = 16 KB
#pragma unroll
    for (int r = 0; r < 4; ++r) {
        const int trow = wv * 16 + g * 4 + r;
        const int grow = row0 + trow;
        const float dv = (grow < M) ? dinv[grow] : 0.f;
#pragma unroll
        for (int nf = 0; nf < 8; nf++)
            ot[trow * 128 + nf * 16 + r16] = bf16_rne(acc[nf][r] * dv);
    }
    __syncthreads();
    {
        const int trow = wv * 16 + r16;       // 16 rows per wave
        const int seg  = g;                   // 4 x 64B segments per row
        const int grow = row0 + trow;
        if (grow < M) {
            const float4* lsrc = (const float4*)ot + trow * 16 + seg * 4;
            float4* gdst = (float4*)((char*)out + (size_t)grow * 256) + seg * 4;
#pragma unroll
            for (int i = 0; i < 4; ++i) gdst[i] = lsrc[i];
        }
    }
}

// ---------------- Aggregation (1 node per wave, 2 bf16 feats per lane) ----------------

template <int OUT32>
__global__ __launch_bounds__(256) void agg_kernel(
        const unsigned short* __restrict__ h, const int* __restrict__ rowp,
        const int* __restrict__ col, const float* __restrict__ dinv,
        const float* __restrict__ bias, void* __restrict__ outv, int n) {
    const int wave = threadIdx.x >> 6;
    const int lane = threadIdx.x & 63;
    const int node = (blockIdx.x << 2) + wave;
    if (node >= n) return;
    const int f = lane << 1;
    int e = rowp[node];
    const int end = rowp[node + 1];
    float a0 = 0.f, a1 = 0.f;
    for (; e + 4 <= end; e += 4) {
        int c0 = col[e], c1 = col[e + 1], c2 = col[e + 2], c3 = col[e + 3];
        unsigned v0 = *(const unsigned*)(h + (size_t)c0 * OUT_DIM + f);
        unsigned v1 = *(const unsigned*)(h + (size_t)c1 * OUT_DIM + f);
        unsigned v2 = *(const unsigned*)(h + (size_t)c2 * OUT_DIM + f);
        unsigned v3 = *(const unsigned*)(h + (size_t)c3 * OUT_DIM + f);
        a0 += __uint_as_float(v0 << 16) + __uint_as_float(v1 << 16)
            + __uint_as_float(v2 << 16) + __uint_as_float(v3 << 16);
        a1 += __uint_as_float(v0 & 0xFFFF0000u) + __uint_as_float(v1 & 0xFFFF0000u)
            + __uint_as_float(v2 & 0xFFFF0000u) + __uint_as_float(v3 & 0xFFFF0000u);
    }
    for (; e < end; ++e) {
        unsigned v = *(const unsigned*)(h + (size_t)col[e] * OUT_DIM + f);
        a0 += __uint_as_float(v << 16);
        a1 += __uint_as_float(v & 0xFFFF0000u);
    }
    float dn = dinv[node];
    a0 = fmaf(a0, dn, bias[f]);
    a1 = fmaf(a1, dn, bias[f + 1]);
    if (OUT32) {
        ((float2*)outv)[(size_t)node * 64 + lane] = make_float2(a0, a1);
    } else {
        unsigned p = ((unsigned)bf16_rne(a1) << 16) | (unsigned)bf16_rne(a0);
        ((unsigned*)outv)[(size_t)node * 64 + lane] = p;
    }
}

// ---------------- BN stats over bf16 buffer ----------------

__global__ __launch_bounds__(256) void bn_stats(const unsigned short* __restrict__ h,
                                                float* __restrict__ stats, int n) {
    const int wave = threadIdx.x >> 6;
    const int lane = threadIdx.x & 63;
    const int f = lane << 1;
    float s0 = 0.f, s1 = 0.f, q0 = 0.f, q1 = 0.f;
    for (int node = (blockIdx.x << 2) + wave; node < n; node += (gridDim.x << 2)) {
        unsigned v = *(const unsigned*)(h + (size_t)node * OUT_DIM + f);
        float x0 = __uint_as_float(v << 16);
        float x1 = __uint_as_float(v & 0xFFFF0000u);
        s0 += x0; s1 += x1;
        q0 = fmaf(x0, x0, q0); q1 = fmaf(x1, x1, q1);
    }
    __shared__ float red[4][256];
    red[wave][f] = s0;        red[wave][f + 1] = s1;
    red[wave][128 + f] = q0;  red[wave][128 + f + 1] = q1;
    __syncthreads();
    int t = threadIdx.x;
    float v = red[0][t] + red[1][t] + red[2][t] + red[3][t];
    atomicAdd(&stats[t], v);
}

__global__ void bn_finalize(const float* __restrict__ stats, const float* __restrict__ g,
                            const float* __restrict__ be, float* __restrict__ bnp, float inv_n) {
    int f = threadIdx.x;  // 128
    float mean = stats[f] * inv_n;
    float var = stats[128 + f] * inv_n - mean * mean;
    var = fmaxf(var, 0.f);
    float sc = g[f] * rsqrtf(var + BN_EPS);
    bnp[f] = sc;
    bnp[128 + f] = be[f] - mean * sc;
}

// ---------------- launch ----------------

extern "C" void kernel_launch(void* const* d_in, const int* in_sizes, int n_in,
                              void* d_out, int out_size, void* d_ws, size_t ws_size,
                              hipStream_t stream) {
    const float* x   = (const float*)d_in[0];
    const int*   ei  = (const int*)d_in[1];
    const float* W1  = (const float*)d_in[2];
    const float* b1  = (const float*)d_in[3];
    const float* W2  = (const float*)d_in[4];
    const float* b2  = (const float*)d_in[5];
    const float* W3  = (const float*)d_in[6];
    const float* b3  = (const float*)d_in[7];
    const float* g1  = (const float*)d_in[8];
    const float* be1 = (const float*)d_in[9];
    const float* g2  = (const float*)d_in[10];
    const float* be2 = (const float*)d_in[11];
    const float* a1  = (const float*)d_in[12];
    const float* a2  = (const float*)d_in[13];

    const int n = N_NODES;
    const int E = in_sizes[1] / 2;
    float* out = (float*)d_out;

    char* ws = (char*)d_ws;
    size_t off = 0;
    auto alloc = [&](size_t bytes) { void* p = ws + off; off += (bytes + 255) & ~(size_t)255; return p; };
    unsigned short* bufA = (unsigned short*)alloc((size_t)n * OUT_DIM * sizeof(short)); // GEMM out (bf16)
    unsigned short* hb   = (unsigned short*)alloc((size_t)n * OUT_DIM * sizeof(short)); // agg out (bf16)
    int*   cnt   = (int*)alloc((size_t)n * sizeof(int));
    int*   rowp  = (int*)alloc((size_t)(n + 1) * sizeof(int));
    float* dinv  = (float*)alloc((size_t)n * sizeof(float));
    int*   col   = (int*)alloc((size_t)(E + n) * sizeof(int));
    float* stats = (float*)alloc(512 * sizeof(float));
    float* bnp1  = (float*)alloc(256 * sizeof(float));
    float* bnp2  = (float*)alloc(256 * sizeof(float));
    short* Wt1   = (short*)alloc((size_t)IN_DIM * OUT_DIM * sizeof(short));
    short* Wt2   = (short*)alloc((size_t)OUT_DIM * OUT_DIM * sizeof(short));
    short* Wt3   = (short*)alloc((size_t)OUT_DIM * OUT_DIM * sizeof(short));

    hipLaunchKernelGGL(init_kernel, dim3((n + 255) / 256), dim3(256), 0, stream, cnt, stats, n);
    hipLaunchKernelGGL(deg_kernel, dim3((E + 255) / 256), dim3(256), 0, stream, ei, cnt, E);
    hipLaunchKernelGGL(scan_kernel, dim3(1), dim3(1024), 0, stream, cnt, rowp, n);
    hipLaunchKernelGGL(selfloop_kernel, dim3((n + 255) / 256), dim3(256), 0, stream, cnt, rowp, dinv, col, n);
    hipLaunchKernelGGL(fill_kernel, dim3((E + 255) / 256), dim3(256), 0, stream, ei, cnt, col, E);
    hipLaunchKernelGGL(wconv_kernel, dim3(IN_DIM / 64), dim3(256), 0, stream, W1, Wt1, IN_DIM);
    hipLaunchKernelGGL(wconv_kernel, dim3(OUT_DIM / 64), dim3(256), 0, stream, W2, Wt2, OUT_DIM);
    hipLaunchKernelGGL(wconv_kernel, dim3(OUT_DIM / 64), dim3(256), 0, stream, W3, Wt3, OUT_DIM);

    const int gblocks = (n + 63) / 64;        // 64 rows per block
    const int ablocks = (n + 3) / 4;          // one node per wave
    // layer 1
    hipLaunchKernelGGL((mfma_gemm<float, IN_DIM, false>), dim3(gblocks), dim3(256), 0, stream,
                       x, Wt1, bufA, n, nullptr, nullptr, dinv);
    hipLaunchKernelGGL((agg_kernel<0>), dim3(ablocks), dim3(256), 0, stream,
                       bufA, rowp, col, dinv, b1, hb, n);
    hipLaunchKernelGGL(bn_stats, dim3(256), dim3(256), 0, stream, hb, stats, n);
    hipLaunchKernelGGL(bn_finalize, dim3(1), dim3(128), 0, stream, stats, g1, be1, bnp1, 1.0f / n);
    // layer 2
    hipLaunchKernelGGL((mfma_gemm<short, OUT_DIM, true>), dim3(gblocks), dim3(256), 0, stream,
                       (const short*)hb, Wt2, bufA, n, bnp1, a1, dinv);
    hipLaunchKernelGGL((agg_kernel<0>), dim3(ablocks), dim3(256), 0, stream,
                       bufA, rowp, col, dinv, b2, hb, n);
    hipLaunchKernelGGL(bn_stats, dim3(256), dim3(256), 0, stream, hb, stats + 256, n);
    hipLaunchKernelGGL(bn_finalize, dim3(1), dim3(128), 0, stream, stats + 256, g2, be2, bnp2, 1.0f / n);
    // layer 3
    hipLaunchKernelGGL((mfma_gemm<short, OUT_DIM, true>), dim3(gblocks), dim3(256), 0, stream,
                       (const short*)hb, Wt3, bufA, n, bnp2, a2, dinv);
    hipLaunchKernelGGL((agg_kernel<1>), dim3(ablocks), dim3(256), 0, stream,
                       bufA, rowp, col, dinv, b3, out, n);
}

// Round 7
// 318.401 us; speedup vs baseline: 3.3037x; 1.2055x over previous
//
#include <hip/hip_runtime.h>

#define N_NODES 50000
#define IN_DIM  512
#define OUT_DIM 128
#define BN_EPS  1e-5f

typedef __attribute__((ext_vector_type(8))) short short8;
typedef __attribute__((ext_vector_type(4))) float f32x4;

__device__ __forceinline__ unsigned short bf16_rne(float x) {
    unsigned u = __float_as_uint(x);
    unsigned r = (u + 0x7FFFu + ((u >> 16) & 1u)) >> 16;
    return (unsigned short)r;
}
__device__ __forceinline__ float bf16_to_f(unsigned short s) {
    return __uint_as_float(((unsigned)s) << 16);
}

// global -> LDS direct staging, 16B per lane. lds dest is wave-uniform;
// HW adds lane*16.
__device__ __forceinline__ void gload16(const void* g, void* l) {
    __builtin_amdgcn_global_load_lds(
        (const __attribute__((address_space(1))) void*)g,
        (__attribute__((address_space(3))) void*)l, 16, 0, 0);
}

// ---------------- CSR build ----------------

__global__ void init_kernel(int* __restrict__ cnt, float* __restrict__ stats, int n) {
    int i = blockIdx.x * blockDim.x + threadIdx.x;
    if (i < n) cnt[i] = 1;            // self-loop contributes 1 to every in-degree
    if (i < 512) stats[i] = 0.f;      // zero BN stat accumulators (both layers)
}

__device__ __forceinline__ int edge_is64(const int* ei) {
    return (ei[1] | ei[3] | ei[5] | ei[7]) == 0;
}

__global__ void deg_kernel(const int* __restrict__ ei, int* __restrict__ cnt, int E) {
    int e = blockIdx.x * blockDim.x + threadIdx.x;
    if (e >= E) return;
    int dst;
    if (edge_is64(ei)) dst = ((const int2*)ei)[E + e].x;
    else               dst = ei[E + e];
    atomicAdd(&cnt[dst], 1);
}

// ---- 3-phase multi-block exclusive scan of cnt[0..n) -> rowp[0..n] ----

__global__ __launch_bounds__(1024) void scan_partial(const int* __restrict__ cnt,
                                                     int* __restrict__ psum, int n) {
    __shared__ int wsum[16];
    const int i = blockIdx.x * 1024 + threadIdx.x;
    const int lane = threadIdx.x & 63;
    const int wv = threadIdx.x >> 6;
    int v = (i < n) ? cnt[i] : 0;
#pragma unroll
    for (int d = 1; d < 64; d <<= 1) v += __shfl_xor(v, d);
    if (lane == 0) wsum[wv] = v;
    __syncthreads();
    if (threadIdx.x == 0) {
        int t = 0;
#pragma unroll
        for (int w = 0; w < 16; ++w) t += wsum[w];
        psum[blockIdx.x] = t;
    }
}

__global__ void scan_base(const int* __restrict__ psum, int* __restrict__ pbase,
                          int* __restrict__ rowp, int nb, int n) {
    const int lane = threadIdx.x;   // 64
    int orig = (lane < nb) ? psum[lane] : 0;
    int v = orig;
#pragma unroll
    for (int d = 1; d < 64; d <<= 1) {
        int t = __shfl_up(v, d);
        if (lane >= d) v += t;
    }
    if (lane < nb) pbase[lane] = v - orig;
    if (lane == nb - 1) rowp[n] = v;
}

__global__ __launch_bounds__(1024) void scan_final(const int* __restrict__ cnt,
                                                   const int* __restrict__ pbase,
                                                   int* __restrict__ rowp, int n) {
    __shared__ int wsum[16];
    const int i = blockIdx.x * 1024 + threadIdx.x;
    const int lane = threadIdx.x & 63;
    const int wv = threadIdx.x >> 6;
    int orig = (i < n) ? cnt[i] : 0;
    int v = orig;
#pragma unroll
    for (int d = 1; d < 64; d <<= 1) {
        int t = __shfl_up(v, d);
        if (lane >= d) v += t;
    }
    if (lane == 63) wsum[wv] = v;
    __syncthreads();
    int woff = 0;
    for (int w = 0; w < wv; ++w) woff += wsum[w];
    if (i < n) rowp[i] = pbase[blockIdx.x] + woff + v - orig;
}

// dinv, self-loop entry, init fill cursor (reuses cnt)
__global__ void selfloop_kernel(int* __restrict__ cnt, const int* __restrict__ rowp,
                                float* __restrict__ dinv, unsigned short* __restrict__ col,
                                int n) {
    int i = blockIdx.x * blockDim.x + threadIdx.x;
    if (i >= n) return;
    int deg = cnt[i];
    dinv[i] = rsqrtf(fmaxf((float)deg, 1.f));
    int rp = rowp[i];
    col[rp] = (unsigned short)i;   // self loop first
    cnt[i] = rp + 1;               // cursor for edge fill
}

__global__ void fill_kernel(const int* __restrict__ ei, int* __restrict__ cnt,
                            unsigned short* __restrict__ col, int E) {
    int e = blockIdx.x * blockDim.x + threadIdx.x;
    if (e >= E) return;
    int src, dst;
    if (edge_is64(ei)) { src = ((const int2*)ei)[e].x; dst = ((const int2*)ei)[E + e].x; }
    else               { src = ei[e];                  dst = ei[E + e]; }
    int pos = atomicAdd(&cnt[dst], 1);
    col[pos] = (unsigned short)src;
}

// ---------------- W convert+transpose: [K][128] fp32 -> [128][K] bf16 ----------------

__global__ __launch_bounds__(256) void wconv_kernel(const float* __restrict__ W,
                                                    short* __restrict__ Wt, int K) {
    __shared__ short tile[64][130];
    const int k0 = blockIdx.x * 64;
    for (int i = threadIdx.x; i < 64 * 128; i += 256) {
        int k = i >> 7, c = i & 127;
        tile[k][c] = (short)bf16_rne(W[(size_t)(k0 + k) * 128 + c]);
    }
    __syncthreads();
    for (int i = threadIdx.x; i < 64 * 128; i += 256) {
        int c = i >> 6, k = i & 63;
        Wt[(size_t)c * K + k0 + k] = tile[k][c];
    }
}

// ---------------- MFMA GEMM, global_load_lds staged (m97 structure) ----------------

template <typename TA, int K, bool XFORM>
__global__ __launch_bounds__(256) void mfma_gemm(
        const TA* __restrict__ A, const short* __restrict__ Wt,
        unsigned short* __restrict__ out, int M,
        const float* __restrict__ bnp, const float* __restrict__ alpha_p,
        const float* __restrict__ dinv) {
    constexpr int BK = 64;
    constexpr int NSTEP = K / BK;
    constexpr int UPRA = (BK * (int)sizeof(TA)) / 16;   // 16B units per A row
    constexpr int AINST = 64 * UPRA / 256;              // 4 (fp32) or 2 (bf16)
    __shared__ TA    ldsA[64 * BK];
    __shared__ short ldsB[128 * BK];

    const int tid  = threadIdx.x;
    const int lane = tid & 63;
    const int wv   = tid >> 6;
    const int r16  = lane & 15;
    const int g    = lane >> 4;
    const int row0 = blockIdx.x * 64;
    const int arow_t = wv * 16 + r16;

    const float alpha = XFORM ? alpha_p[0] : 0.f;

    f32x4 acc[8];
#pragma unroll
    for (int nf = 0; nf < 8; nf++) acc[nf] = (f32x4)(0.f);

    for (int s = 0; s < NSTEP; ++s) {
        const int k0 = s * BK;
        if (s) __syncthreads();
#pragma unroll
        for (int i = 0; i < AINST; ++i) {
            const int d   = i * 256 + tid;
            const int row = d / UPRA, p = d % UPRA;
            int grow = row0 + row; if (grow >= M) grow = M - 1;
            const char* src = (const char*)(A + (size_t)grow * K + k0) + ((p ^ (row & 7)) * 16);
            gload16(src, (char*)ldsA + (size_t)(i * 256 + wv * 64) * 16);
        }
#pragma unroll
        for (int i = 0; i < 4; ++i) {
            const int d    = i * 256 + tid;
            const int colb = d >> 3, p = d & 7;
            const short* src = Wt + (size_t)colb * K + k0 + (p ^ (colb & 7)) * 8;
            gload16(src, (char*)ldsB + (size_t)(i * 256 + wv * 64) * 16);
        }
        __syncthreads();
#pragma unroll
        for (int ksub = 0; ksub < 2; ++ksub) {
            short8 af;
            if constexpr (sizeof(TA) == 4) {
                const int q0 = ksub * 8 + g * 2;
                const float4* A4 = (const float4*)ldsA;
                float4 alo = A4[arow_t * UPRA + (q0 ^ (r16 & 7))];
                float4 ahi = A4[arow_t * UPRA + ((q0 + 1) ^ (r16 & 7))];
                float av[8] = {alo.x, alo.y, alo.z, alo.w, ahi.x, ahi.y, ahi.z, ahi.w};
#pragma unroll
                for (int j = 0; j < 8; j++) af[j] = (short)bf16_rne(av[j]);
            } else {
                short8 raw = ((const short8*)ldsA)[arow_t * 8 + ((ksub * 4 + g) ^ (r16 & 7))];
                if constexpr (XFORM) {
                    const int kk = k0 + ksub * 32 + g * 8;
#pragma unroll
                    for (int j = 0; j < 8; j++) {
                        float v = fmaf(bf16_to_f((unsigned short)raw[j]), bnp[kk + j], bnp[128 + kk + j]);
                        v = v >= 0.f ? v : alpha * v;
                        af[j] = (short)bf16_rne(v);
                    }
                } else {
                    af = raw;
                }
            }
#pragma unroll
            for (int nf = 0; nf < 8; nf++) {
                const int colb = nf * 16 + r16;
                short8 bf = ((const short8*)ldsB)[colb * 8 + ((ksub * 4 + g) ^ (r16 & 7))];
                acc[nf] = __builtin_amdgcn_mfma_f32_16x16x32_bf16(af, bf, acc[nf], 0, 0, 0);
            }
        }
    }

    // epilogue: acc -> LDS (bf16, reuse ldsB) -> coalesced stores
    __syncthreads();
    unsigned short* ot = (unsigned short*)ldsB;
#pragma unroll
    for (int r = 0; r < 4; ++r) {
        const int trow = wv * 16 + g * 4 + r;
        const int grow = row0 + trow;
        const float dv = (grow < M) ? dinv[grow] : 0.f;
#pragma unroll
        for (int nf = 0; nf < 8; nf++)
            ot[trow * 128 + nf * 16 + r16] = bf16_rne(acc[nf][r] * dv);
    }
    __syncthreads();
    {
        const int trow = wv * 16 + r16;
        const int seg  = g;
        const int grow = row0 + trow;
        if (grow < M) {
            const float4* lsrc = (const float4*)ot + trow * 16 + seg * 4;
            float4* gdst = (float4*)((char*)out + (size_t)grow * 256) + seg * 4;
#pragma unroll
            for (int i = 0; i < 4; ++i) gdst[i] = lsrc[i];
        }
    }
}

// ---------------- Aggregation (1 node per wave, 2 bf16 feats per lane) ----------------

template <int OUT32>
__global__ __launch_bounds__(256) void agg_kernel(
        const unsigned short* __restrict__ h, const int* __restrict__ rowp,
        const unsigned short* __restrict__ col, const float* __restrict__ dinv,
        const float* __restrict__ bias, void* __restrict__ outv, int n) {
    const int wave = threadIdx.x >> 6;
    const int lane = threadIdx.x & 63;
    const int node = (blockIdx.x << 2) + wave;
    if (node >= n) return;
    const int f = lane << 1;
    int e = rowp[node];
    const int end = rowp[node + 1];
    float a0 = 0.f, a1 = 0.f;
    for (; e + 8 <= end; e += 8) {
        int c[8];
#pragma unroll
        for (int j = 0; j < 8; j++) c[j] = col[e + j];
        unsigned v[8];
#pragma unroll
        for (int j = 0; j < 8; j++) v[j] = *(const unsigned*)(h + (size_t)c[j] * OUT_DIM + f);
#pragma unroll
        for (int j = 0; j < 8; j++) {
            a0 += __uint_as_float(v[j] << 16);
            a1 += __uint_as_float(v[j] & 0xFFFF0000u);
        }
    }
    for (; e < end; ++e) {
        unsigned v = *(const unsigned*)(h + (size_t)col[e] * OUT_DIM + f);
        a0 += __uint_as_float(v << 16);
        a1 += __uint_as_float(v & 0xFFFF0000u);
    }
    float dn = dinv[node];
    a0 = fmaf(a0, dn, bias[f]);
    a1 = fmaf(a1, dn, bias[f + 1]);
    if (OUT32) {
        ((float2*)outv)[(size_t)node * 64 + lane] = make_float2(a0, a1);
    } else {
        unsigned p = ((unsigned)bf16_rne(a1) << 16) | (unsigned)bf16_rne(a0);
        ((unsigned*)outv)[(size_t)node * 64 + lane] = p;
    }
}

// ---------------- BN stats over bf16 buffer ----------------

__global__ __launch_bounds__(256) void bn_stats(const unsigned short* __restrict__ h,
                                                float* __restrict__ stats, int n) {
    const int wave = threadIdx.x >> 6;
    const int lane = threadIdx.x & 63;
    const int f = lane << 1;
    float s0 = 0.f, s1 = 0.f, q0 = 0.f, q1 = 0.f;
    for (int node = (blockIdx.x << 2) + wave; node < n; node += (gridDim.x << 2)) {
        unsigned v = *(const unsigned*)(h + (size_t)node * OUT_DIM + f);
        float x0 = __uint_as_float(v << 16);
        float x1 = __uint_as_float(v & 0xFFFF0000u);
        s0 += x0; s1 += x1;
        q0 = fmaf(x0, x0, q0); q1 = fmaf(x1, x1, q1);
    }
    __shared__ float red[4][256];
    red[wave][f] = s0;        red[wave][f + 1] = s1;
    red[wave][128 + f] = q0;  red[wave][128 + f + 1] = q1;
    __syncthreads();
    int t = threadIdx.x;
    float v = red[0][t] + red[1][t] + red[2][t] + red[3][t];
    atomicAdd(&stats[t], v);
}

__global__ void bn_finalize(const float* __restrict__ stats, const float* __restrict__ g,
                            const float* __restrict__ be, float* __restrict__ bnp, float inv_n) {
    int f = threadIdx.x;  // 128
    float mean = stats[f] * inv_n;
    float var = stats[128 + f] * inv_n - mean * mean;
    var = fmaxf(var, 0.f);
    float sc = g[f] * rsqrtf(var + BN_EPS);
    bnp[f] = sc;
    bnp[128 + f] = be[f] - mean * sc;
}

// ---------------- launch ----------------

extern "C" void kernel_launch(void* const* d_in, const int* in_sizes, int n_in,
                              void* d_out, int out_size, void* d_ws, size_t ws_size,
                              hipStream_t stream) {
    const float* x   = (const float*)d_in[0];
    const int*   ei  = (const int*)d_in[1];
    const float* W1  = (const float*)d_in[2];
    const float* b1  = (const float*)d_in[3];
    const float* W2  = (const float*)d_in[4];
    const float* b2  = (const float*)d_in[5];
    const float* W3  = (const float*)d_in[6];
    const float* b3  = (const float*)d_in[7];
    const float* g1  = (const float*)d_in[8];
    const float* be1 = (const float*)d_in[9];
    const float* g2  = (const float*)d_in[10];
    const float* be2 = (const float*)d_in[11];
    const float* a1  = (const float*)d_in[12];
    const float* a2  = (const float*)d_in[13];

    const int n = N_NODES;
    const int E = in_sizes[1] / 2;
    float* out = (float*)d_out;

    char* ws = (char*)d_ws;
    size_t off = 0;
    auto alloc = [&](size_t bytes) { void* p = ws + off; off += (bytes + 255) & ~(size_t)255; return p; };
    unsigned short* bufA = (unsigned short*)alloc((size_t)n * OUT_DIM * sizeof(short)); // GEMM out (bf16)
    unsigned short* hb   = (unsigned short*)alloc((size_t)n * OUT_DIM * sizeof(short)); // agg out (bf16)
    int*   cnt   = (int*)alloc((size_t)n * sizeof(int));
    int*   rowp  = (int*)alloc((size_t)(n + 1) * sizeof(int));
    float* dinv  = (float*)alloc((size_t)n * sizeof(float));
    unsigned short* col = (unsigned short*)alloc((size_t)(E + n) * sizeof(unsigned short));
    float* stats = (float*)alloc(512 * sizeof(float));
    float* bnp1  = (float*)alloc(256 * sizeof(float));
    float* bnp2  = (float*)alloc(256 * sizeof(float));
    short* Wt1   = (short*)alloc((size_t)IN_DIM * OUT_DIM * sizeof(short));
    short* Wt2   = (short*)alloc((size_t)OUT_DIM * OUT_DIM * sizeof(short));
    short* Wt3   = (short*)alloc((size_t)OUT_DIM * OUT_DIM * sizeof(short));
    int*   psum  = (int*)alloc(64 * sizeof(int));
    int*   pbase = (int*)alloc(64 * sizeof(int));

    const int nbScan = (n + 1023) / 1024;     // 49

    hipLaunchKernelGGL(init_kernel, dim3((n + 255) / 256), dim3(256), 0, stream, cnt, stats, n);
    hipLaunchKernelGGL(deg_kernel, dim3((E + 255) / 256), dim3(256), 0, stream, ei, cnt, E);
    hipLaunchKernelGGL(scan_partial, dim3(nbScan), dim3(1024), 0, stream, cnt, psum, n);
    hipLaunchKernelGGL(scan_base, dim3(1), dim3(64), 0, stream, psum, pbase, rowp, nbScan, n);
    hipLaunchKernelGGL(scan_final, dim3(nbScan), dim3(1024), 0, stream, cnt, pbase, rowp, n);
    hipLaunchKernelGGL(selfloop_kernel, dim3((n + 255) / 256), dim3(256), 0, stream, cnt, rowp, dinv, col, n);
    hipLaunchKernelGGL(fill_kernel, dim3((E + 255) / 256), dim3(256), 0, stream, ei, cnt, col, E);
    hipLaunchKernelGGL(wconv_kernel, dim3(IN_DIM / 64), dim3(256), 0, stream, W1, Wt1, IN_DIM);
    hipLaunchKernelGGL(wconv_kernel, dim3(OUT_DIM / 64), dim3(256), 0, stream, W2, Wt2, OUT_DIM);
    hipLaunchKernelGGL(wconv_kernel, dim3(OUT_DIM / 64), dim3(256), 0, stream, W3, Wt3, OUT_DIM);

    const int gblocks = (n + 63) / 64;        // 64 rows per block
    const int ablocks = (n + 3) / 4;          // one node per wave
    // layer 1
    hipLaunchKernelGGL((mfma_gemm<float, IN_DIM, false>), dim3(gblocks), dim3(256), 0, stream,
                       x, Wt1, bufA, n, nullptr, nullptr, dinv);
    hipLaunchKernelGGL((agg_kernel<0>), dim3(ablocks), dim3(256), 0, stream,
                       bufA, rowp, col, dinv, b1, hb, n);
    hipLaunchKernelGGL(bn_stats, dim3(256), dim3(256), 0, stream, hb, stats, n);
    hipLaunchKernelGGL(bn_finalize, dim3(1), dim3(128), 0, stream, stats, g1, be1, bnp1, 1.0f / n);
    // layer 2
    hipLaunchKernelGGL((mfma_gemm<short, OUT_DIM, true>), dim3(gblocks), dim3(256), 0, stream,
                       (const short*)hb, Wt2, bufA, n, bnp1, a1, dinv);
    hipLaunchKernelGGL((agg_kernel<0>), dim3(ablocks), dim3(256), 0, stream,
                       bufA, rowp, col, dinv, b2, hb, n);
    hipLaunchKernelGGL(bn_stats, dim3(256), dim3(256), 0, stream, hb, stats + 256, n);
    hipLaunchKernelGGL(bn_finalize, dim3(1), dim3(128), 0, stream, stats + 256, g2, be2, bnp2, 1.0f / n);
    // layer 3
    hipLaunchKernelGGL((mfma_gemm<short, OUT_DIM, true>), dim3(gblocks), dim3(256), 0, stream,
                       (const short*)hb, Wt3, bufA, n, bnp2, a2, dinv);
    hipLaunchKernelGGL((agg_kernel<1>), dim3(ablocks), dim3(256), 0, stream,
                       bufA, rowp, col, dinv, b3, out, n);
}

// Round 8
// 280.920 us; speedup vs baseline: 3.7445x; 1.1334x over previous
//
#include <hip/hip_runtime.h>

#define N_NODES 50000
#define IN_DIM  512
#define OUT_DIM 128
#define BN_EPS  1e-5f

typedef __attribute__((ext_vector_type(8))) short short8;
typedef __attribute__((ext_vector_type(4))) float f32x4;

__device__ __forceinline__ unsigned short bf16_rne(float x) {
    unsigned u = __float_as_uint(x);
    unsigned r = (u + 0x7FFFu + ((u >> 16) & 1u)) >> 16;
    return (unsigned short)r;
}
__device__ __forceinline__ float bf16_to_f(unsigned short s) {
    return __uint_as_float(((unsigned)s) << 16);
}

// global -> LDS direct staging, 16B per lane. lds dest is wave-uniform;
// HW adds lane*16.
__device__ __forceinline__ void gload16(const void* g, void* l) {
    __builtin_amdgcn_global_load_lds(
        (const __attribute__((address_space(1))) void*)g,
        (__attribute__((address_space(3))) void*)l, 16, 0, 0);
}

// ---------------- CSR build ----------------

__global__ void init_kernel(int* __restrict__ cnt, float* __restrict__ stats, int n) {
    int i = blockIdx.x * blockDim.x + threadIdx.x;
    if (i < n) cnt[i] = 1;             // self-loop contributes 1 to every in-degree
    if (i < 4096) stats[i] = 0.f;      // 2 layers x 8 replicas x 256
}

__device__ __forceinline__ int edge_is64(const int* ei) {
    return (ei[1] | ei[3] | ei[5] | ei[7]) == 0;
}

__global__ void deg_kernel(const int* __restrict__ ei, int* __restrict__ cnt, int E) {
    int e = blockIdx.x * blockDim.x + threadIdx.x;
    if (e >= E) return;
    int dst;
    if (edge_is64(ei)) dst = ((const int2*)ei)[E + e].x;
    else               dst = ei[E + e];
    atomicAdd(&cnt[dst], 1);
}

// ---- 3-phase multi-block exclusive scan; final phase also does selfloop ----

__global__ __launch_bounds__(1024) void scan_partial(const int* __restrict__ cnt,
                                                     int* __restrict__ psum, int n) {
    __shared__ int wsum[16];
    const int i = blockIdx.x * 1024 + threadIdx.x;
    const int lane = threadIdx.x & 63;
    const int wv = threadIdx.x >> 6;
    int v = (i < n) ? cnt[i] : 0;
#pragma unroll
    for (int d = 1; d < 64; d <<= 1) v += __shfl_xor(v, d);
    if (lane == 0) wsum[wv] = v;
    __syncthreads();
    if (threadIdx.x == 0) {
        int t = 0;
#pragma unroll
        for (int w = 0; w < 16; ++w) t += wsum[w];
        psum[blockIdx.x] = t;
    }
}

__global__ void scan_base(const int* __restrict__ psum, int* __restrict__ pbase,
                          int* __restrict__ rowp, int nb, int n) {
    const int lane = threadIdx.x;   // 64
    int orig = (lane < nb) ? psum[lane] : 0;
    int v = orig;
#pragma unroll
    for (int d = 1; d < 64; d <<= 1) {
        int t = __shfl_up(v, d);
        if (lane >= d) v += t;
    }
    if (lane < nb) pbase[lane] = v - orig;
    if (lane == nb - 1) rowp[n] = v;
}

// final scan + dinv + self-loop entry + fill-cursor init (merged selfloop)
__global__ __launch_bounds__(1024) void scan_final(int* __restrict__ cnt,
                                                   const int* __restrict__ pbase,
                                                   int* __restrict__ rowp,
                                                   float* __restrict__ dinv,
                                                   unsigned short* __restrict__ col, int n) {
    __shared__ int wsum[16];
    const int i = blockIdx.x * 1024 + threadIdx.x;
    const int lane = threadIdx.x & 63;
    const int wv = threadIdx.x >> 6;
    int orig = (i < n) ? cnt[i] : 0;
    int v = orig;
#pragma unroll
    for (int d = 1; d < 64; d <<= 1) {
        int t = __shfl_up(v, d);
        if (lane >= d) v += t;
    }
    if (lane == 63) wsum[wv] = v;
    __syncthreads();
    int woff = 0;
    for (int w = 0; w < wv; ++w) woff += wsum[w];
    if (i < n) {
        int rp = pbase[blockIdx.x] + woff + v - orig;
        rowp[i] = rp;
        dinv[i] = rsqrtf(fmaxf((float)orig, 1.f));
        col[rp] = (unsigned short)i;   // self loop first
        cnt[i] = rp + 1;               // cursor for edge fill
    }
}

__global__ void fill_kernel(const int* __restrict__ ei, int* __restrict__ cnt,
                            unsigned short* __restrict__ col, int E) {
    int e = blockIdx.x * blockDim.x + threadIdx.x;
    if (e >= E) return;
    int src, dst;
    if (edge_is64(ei)) { src = ((const int2*)ei)[e].x; dst = ((const int2*)ei)[E + e].x; }
    else               { src = ei[e];                  dst = ei[E + e]; }
    int pos = atomicAdd(&cnt[dst], 1);
    col[pos] = (unsigned short)src;
}

// ---------------- W convert+transpose (all 3 weights, one launch) ----------------

__global__ __launch_bounds__(256) void wconv_all(const float* __restrict__ W1, short* __restrict__ Wt1,
                                                 const float* __restrict__ W2, short* __restrict__ Wt2,
                                                 const float* __restrict__ W3, short* __restrict__ Wt3) {
    __shared__ short tile[64][130];
    const int b = blockIdx.x;
    const float* W; short* Wt; int K, k0;
    if (b < 8)       { W = W1; Wt = Wt1; K = IN_DIM;  k0 = b * 64; }
    else if (b < 10) { W = W2; Wt = Wt2; K = OUT_DIM; k0 = (b - 8) * 64; }
    else             { W = W3; Wt = Wt3; K = OUT_DIM; k0 = (b - 10) * 64; }
    for (int i = threadIdx.x; i < 64 * 128; i += 256) {
        int k = i >> 7, c = i & 127;
        tile[k][c] = (short)bf16_rne(W[(size_t)(k0 + k) * 128 + c]);
    }
    __syncthreads();
    for (int i = threadIdx.x; i < 64 * 128; i += 256) {
        int c = i >> 6, k = i & 63;
        Wt[(size_t)c * K + k0 + k] = tile[k][c];
    }
}

// ---------------- MFMA GEMM, global_load_lds staged; BN finalize fused ----------------
// XFORM: block start reduces the 8 stat replicas -> scale/shift in LDS, then
// applies BN+PReLU to A fragments in-register. Epilogue scales rows by dinv.

template <typename TA, int K, bool XFORM>
__global__ __launch_bounds__(256) void mfma_gemm(
        const TA* __restrict__ A, const short* __restrict__ Wt,
        unsigned short* __restrict__ out, int M,
        const float* __restrict__ stats, const float* __restrict__ gam,
        const float* __restrict__ bet, const float* __restrict__ alpha_p,
        const float* __restrict__ dinv) {
    constexpr int BK = 64;
    constexpr int NSTEP = K / BK;
    constexpr int UPRA = (BK * (int)sizeof(TA)) / 16;   // 16B units per A row
    constexpr int AINST = 64 * UPRA / 256;              // 4 (fp32) or 2 (bf16)
    __shared__ TA    ldsA[64 * BK];
    __shared__ short ldsB[128 * BK];
    __shared__ float bnp[256];

    const int tid  = threadIdx.x;
    const int lane = tid & 63;
    const int wv   = tid >> 6;
    const int r16  = lane & 15;
    const int g    = lane >> 4;
    const int row0 = blockIdx.x * 64;
    const int arow_t = wv * 16 + r16;

    float alpha = 0.f;
    if constexpr (XFORM) {
        alpha = alpha_p[0];
        if (tid < 128) {
            float sum = 0.f, sq = 0.f;
#pragma unroll
            for (int r = 0; r < 8; ++r) {
                sum += stats[r * 256 + tid];
                sq  += stats[r * 256 + 128 + tid];
            }
            const float inv_n = 1.0f / (float)N_NODES;
            float mean = sum * inv_n;
            float var = fmaxf(sq * inv_n - mean * mean, 0.f);
            float sc = gam[tid] * rsqrtf(var + BN_EPS);
            bnp[tid] = sc;
            bnp[128 + tid] = bet[tid] - mean * sc;
        }
        __syncthreads();
    }

    f32x4 acc[8];
#pragma unroll
    for (int nf = 0; nf < 8; nf++) acc[nf] = (f32x4)(0.f);

    for (int s = 0; s < NSTEP; ++s) {
        const int k0 = s * BK;
        if (s) __syncthreads();
#pragma unroll
        for (int i = 0; i < AINST; ++i) {
            const int d   = i * 256 + tid;
            const int row = d / UPRA, p = d % UPRA;
            int grow = row0 + row; if (grow >= M) grow = M - 1;
            const char* src = (const char*)(A + (size_t)grow * K + k0) + ((p ^ (row & 7)) * 16);
            gload16(src, (char*)ldsA + (size_t)(i * 256 + wv * 64) * 16);
        }
#pragma unroll
        for (int i = 0; i < 4; ++i) {
            const int d    = i * 256 + tid;
            const int colb = d >> 3, p = d & 7;
            const short* src = Wt + (size_t)colb * K + k0 + (p ^ (colb & 7)) * 8;
            gload16(src, (char*)ldsB + (size_t)(i * 256 + wv * 64) * 16);
        }
        __syncthreads();
#pragma unroll
        for (int ksub = 0; ksub < 2; ++ksub) {
            short8 af;
            if constexpr (sizeof(TA) == 4) {
                const int q0 = ksub * 8 + g * 2;
                const float4* A4 = (const float4*)ldsA;
                float4 alo = A4[arow_t * UPRA + (q0 ^ (r16 & 7))];
                float4 ahi = A4[arow_t * UPRA + ((q0 + 1) ^ (r16 & 7))];
                float av[8] = {alo.x, alo.y, alo.z, alo.w, ahi.x, ahi.y, ahi.z, ahi.w};
#pragma unroll
                for (int j = 0; j < 8; j++) af[j] = (short)bf16_rne(av[j]);
            } else {
                short8 raw = ((const short8*)ldsA)[arow_t * 8 + ((ksub * 4 + g) ^ (r16 & 7))];
                if constexpr (XFORM) {
                    const int kk = ksub * 32 + g * 8;   // K==128: kk + k0 indexes bnp[0..127]
                    const int kb = k0 + kk;
#pragma unroll
                    for (int j = 0; j < 8; j++) {
                        float v = fmaf(bf16_to_f((unsigned short)raw[j]), bnp[kb + j], bnp[128 + kb + j]);
                        v = v >= 0.f ? v : alpha * v;
                        af[j] = (short)bf16_rne(v);
                    }
                } else {
                    af = raw;
                }
            }
#pragma unroll
            for (int nf = 0; nf < 8; nf++) {
                const int colb = nf * 16 + r16;
                short8 bf = ((const short8*)ldsB)[colb * 8 + ((ksub * 4 + g) ^ (r16 & 7))];
                acc[nf] = __builtin_amdgcn_mfma_f32_16x16x32_bf16(af, bf, acc[nf], 0, 0, 0);
            }
        }
    }

    // epilogue: acc -> LDS (bf16, reuse ldsB) -> coalesced stores
    __syncthreads();
    unsigned short* ot = (unsigned short*)ldsB;
#pragma unroll
    for (int r = 0; r < 4; ++r) {
        const int trow = wv * 16 + g * 4 + r;
        const int grow = row0 + trow;
        const float dv = (grow < M) ? dinv[grow] : 0.f;
#pragma unroll
        for (int nf = 0; nf < 8; nf++)
            ot[trow * 128 + nf * 16 + r16] = bf16_rne(acc[nf][r] * dv);
    }
    __syncthreads();
    {
        const int trow = wv * 16 + r16;
        const int seg  = g;
        const int grow = row0 + trow;
        if (grow < M) {
            const float4* lsrc = (const float4*)ot + trow * 16 + seg * 4;
            float4* gdst = (float4*)((char*)out + (size_t)grow * 256) + seg * 4;
#pragma unroll
            for (int i = 0; i < 4; ++i) gdst[i] = lsrc[i];
        }
    }
}

// ---------------- Aggregation + fused BN stats ----------------
// Grid-stride (2048 blocks, 4 nodes/block-iter). FINAL=0: bf16 out + stats
// into 8 replicas (per-block LDS reduce, 256 atomics into replica blk&7).
// FINAL=1: fp32 out, no stats.

template <int FINAL>
__global__ __launch_bounds__(256) void agg_kernel(
        const unsigned short* __restrict__ h, const int* __restrict__ rowp,
        const unsigned short* __restrict__ col, const float* __restrict__ dinv,
        const float* __restrict__ bias, void* __restrict__ outv,
        float* __restrict__ stats, int n) {
    const int wave = threadIdx.x >> 6;
    const int lane = threadIdx.x & 63;
    const int f = lane << 1;
    const float b0 = bias[f], b1 = bias[f + 1];
    float s0 = 0.f, s1 = 0.f, q0 = 0.f, q1 = 0.f;
    const int stride = gridDim.x << 2;
    for (int node = (blockIdx.x << 2) + wave; node < n; node += stride) {
        int e = rowp[node];
        const int end = rowp[node + 1];
        float a0 = 0.f, a1 = 0.f;
        for (; e + 8 <= end; e += 8) {
            int c[8];
#pragma unroll
            for (int j = 0; j < 8; j++) c[j] = col[e + j];
            unsigned v[8];
#pragma unroll
            for (int j = 0; j < 8; j++) v[j] = *(const unsigned*)(h + (size_t)c[j] * OUT_DIM + f);
#pragma unroll
            for (int j = 0; j < 8; j++) {
                a0 += __uint_as_float(v[j] << 16);
                a1 += __uint_as_float(v[j] & 0xFFFF0000u);
            }
        }
        for (; e < end; ++e) {
            unsigned v = *(const unsigned*)(h + (size_t)col[e] * OUT_DIM + f);
            a0 += __uint_as_float(v << 16);
            a1 += __uint_as_float(v & 0xFFFF0000u);
        }
        float dn = dinv[node];
        a0 = fmaf(a0, dn, b0);
        a1 = fmaf(a1, dn, b1);
        if (FINAL) {
            ((float2*)outv)[(size_t)node * 64 + lane] = make_float2(a0, a1);
        } else {
            unsigned p = ((unsigned)bf16_rne(a1) << 16) | (unsigned)bf16_rne(a0);
            ((unsigned*)outv)[(size_t)node * 64 + lane] = p;
            s0 += a0; s1 += a1;
            q0 = fmaf(a0, a0, q0); q1 = fmaf(a1, a1, q1);
        }
    }
    if (!FINAL) {
        __shared__ float red[4][256];
        red[wave][f] = s0;        red[wave][f + 1] = s1;
        red[wave][128 + f] = q0;  red[wave][128 + f + 1] = q1;
        __syncthreads();
        int t = threadIdx.x;
        float v = red[0][t] + red[1][t] + red[2][t] + red[3][t];
        atomicAdd(&stats[(blockIdx.x & 7) * 256 + t], v);
    }
}

// ---------------- launch ----------------

extern "C" void kernel_launch(void* const* d_in, const int* in_sizes, int n_in,
                              void* d_out, int out_size, void* d_ws, size_t ws_size,
                              hipStream_t stream) {
    const float* x   = (const float*)d_in[0];
    const int*   ei  = (const int*)d_in[1];
    const float* W1  = (const float*)d_in[2];
    const float* b1  = (const float*)d_in[3];
    const float* W2  = (const float*)d_in[4];
    const float* b2  = (const float*)d_in[5];
    const float* W3  = (const float*)d_in[6];
    const float* b3  = (const float*)d_in[7];
    const float* g1  = (const float*)d_in[8];
    const float* be1 = (const float*)d_in[9];
    const float* g2  = (const float*)d_in[10];
    const float* be2 = (const float*)d_in[11];
    const float* a1  = (const float*)d_in[12];
    const float* a2  = (const float*)d_in[13];

    const int n = N_NODES;
    const int E = in_sizes[1] / 2;
    float* out = (float*)d_out;

    char* ws = (char*)d_ws;
    size_t off = 0;
    auto alloc = [&](size_t bytes) { void* p = ws + off; off += (bytes + 255) & ~(size_t)255; return p; };
    unsigned short* bufA = (unsigned short*)alloc((size_t)n * OUT_DIM * sizeof(short)); // GEMM out (bf16)
    unsigned short* hb   = (unsigned short*)alloc((size_t)n * OUT_DIM * sizeof(short)); // agg out (bf16)
    int*   cnt   = (int*)alloc((size_t)n * sizeof(int));
    int*   rowp  = (int*)alloc((size_t)(n + 1) * sizeof(int));
    float* dinv  = (float*)alloc((size_t)n * sizeof(float));
    unsigned short* col = (unsigned short*)alloc((size_t)(E + n) * sizeof(unsigned short));
    float* stats = (float*)alloc(4096 * sizeof(float));   // 2 layers x 8 replicas x 256
    short* Wt1   = (short*)alloc((size_t)IN_DIM * OUT_DIM * sizeof(short));
    short* Wt2   = (short*)alloc((size_t)OUT_DIM * OUT_DIM * sizeof(short));
    short* Wt3   = (short*)alloc((size_t)OUT_DIM * OUT_DIM * sizeof(short));
    int*   psum  = (int*)alloc(64 * sizeof(int));
    int*   pbase = (int*)alloc(64 * sizeof(int));

    const int nbScan = (n + 1023) / 1024;     // 49

    hipLaunchKernelGGL(init_kernel, dim3((n + 255) / 256), dim3(256), 0, stream, cnt, stats, n);
    hipLaunchKernelGGL(deg_kernel, dim3((E + 255) / 256), dim3(256), 0, stream, ei, cnt, E);
    hipLaunchKernelGGL(scan_partial, dim3(nbScan), dim3(1024), 0, stream, cnt, psum, n);
    hipLaunchKernelGGL(scan_base, dim3(1), dim3(64), 0, stream, psum, pbase, rowp, nbScan, n);
    hipLaunchKernelGGL(scan_final, dim3(nbScan), dim3(1024), 0, stream, cnt, pbase, rowp, dinv, col, n);
    hipLaunchKernelGGL(fill_kernel, dim3((E + 255) / 256), dim3(256), 0, stream, ei, cnt, col, E);
    hipLaunchKernelGGL(wconv_all, dim3(12), dim3(256), 0, stream, W1, Wt1, W2, Wt2, W3, Wt3);

    const int gblocks = (n + 63) / 64;        // 64 rows per block
    const int ablocks = 2048;                 // grid-stride agg, 8 blocks/CU
    // layer 1
    hipLaunchKernelGGL((mfma_gemm<float, IN_DIM, false>), dim3(gblocks), dim3(256), 0, stream,
                       x, Wt1, bufA, n, nullptr, nullptr, nullptr, nullptr, dinv);
    hipLaunchKernelGGL((agg_kernel<0>), dim3(ablocks), dim3(256), 0, stream,
                       bufA, rowp, col, dinv, b1, hb, stats, n);
    // layer 2
    hipLaunchKernelGGL((mfma_gemm<short, OUT_DIM, true>), dim3(gblocks), dim3(256), 0, stream,
                       (const short*)hb, Wt2, bufA, n, stats, g1, be1, a1, dinv);
    hipLaunchKernelGGL((agg_kernel<0>), dim3(ablocks), dim3(256), 0, stream,
                       bufA, rowp, col, dinv, b2, hb, stats + 2048, n);
    // layer 3
    hipLaunchKernelGGL((mfma_gemm<short, OUT_DIM, true>), dim3(gblocks), dim3(256), 0, stream,
                       (const short*)hb, Wt3, bufA, n, stats + 2048, g2, be2, a2, dinv);
    hipLaunchKernelGGL((agg_kernel<1>), dim3(ablocks), dim3(256), 0, stream,
                       bufA, rowp, col, dinv, b3, out, nullptr, n);
}